// Round 4
// baseline (545.774 us; speedup 1.0000x reference)
//
#include <hip/hip_runtime.h>

typedef short bf16x8 __attribute__((ext_vector_type(8)));
typedef float f32x4 __attribute__((ext_vector_type(4)));
using u16 = unsigned short;
using u32 = unsigned int;

#define MFMA_BF16(A, B, C) __builtin_amdgcn_mfma_f32_16x16x32_bf16((A), (B), (C), 0, 0, 0)

#define CC 256
#define DD 256
#define KK 8192
#define NN 16384     // B*H*W
#define HW 1024      // H*W
#define OUT0 4194304 // B*D*H*W

static __device__ __forceinline__ float b2f(u16 u) {
    union { u32 i; float f; } v; v.i = ((u32)u) << 16; return v.f;
}
static __device__ __forceinline__ u16 f2b(float f) {  // RNE fp32 -> bf16
    union { float f; u32 i; } v; v.f = f;
    u32 x = v.i;
    u32 r = (x + 0x7fffu + ((x >> 16) & 1u)) >> 16;
    return (u16)r;
}
static __device__ __forceinline__ void split3(float v, u16& h, u16& m, u16& l) {
    h = f2b(v); float r1 = v - b2f(h);
    m = f2b(r1); float r2 = r1 - b2f(m);
    l = f2b(r2);
}

// ---------------------------------------------------------------------------
// K0a: transpose codebook (D,K) fp32 -> cbT (K,D) fp32 (ws) + cbTh (K,D) bf16.
// cbTh lives in d_out chunk-0 scratch (16.7 MB fp32 region, fully rewritten
// by k_gather at the end).
__global__ __launch_bounds__(256) void k_canon(const float* __restrict__ cb,
                                               float* __restrict__ cbT,
                                               u16* __restrict__ cbTh) {
    __shared__ float tile[32][33];
    int k0 = blockIdx.x * 32, d0 = blockIdx.y * 32;
    int tx = threadIdx.x, ty = threadIdx.y;  // 32 x 8
#pragma unroll
    for (int i = 0; i < 4; i++) {
        int d = d0 + ty + i * 8;
        tile[ty + i * 8][tx] = cb[d * KK + k0 + tx];
    }
    __syncthreads();
#pragma unroll
    for (int i = 0; i < 4; i++) {
        int k = k0 + ty + i * 8;
        float v = tile[tx][ty + i * 8];
        cbT[k * DD + d0 + tx] = v;
        cbTh[k * DD + d0 + tx] = f2b(v);
    }
}

// ---------------------------------------------------------------------------
// K0b: cbn[k] = sum_d cb[d,k]^2 (fp32; approx scores only); zero scal.
__global__ __launch_bounds__(256) void k_cbnorm(const float* __restrict__ cb,
                                                float* __restrict__ cbn,
                                                float* __restrict__ scal) {
    int k = blockIdx.x * 256 + threadIdx.x;
    float s = 0.f;
    for (int d = 0; d < DD; d++) {
        float v = cb[d * KK + k];
        s += v * v;
    }
    cbn[k] = s;
    if (k == 0) scal[0] = 0.f;
}

// ---------------------------------------------------------------------------
// K1: xp = x_r @ W^T + b via bf16x3 split MFMA (6 terms ~ fp32 accuracy).
// One wave per 16 rows. xp fp32 (n,d).
__global__ __launch_bounds__(256) void k_proj(const float* __restrict__ x,
                                              const float* __restrict__ Wm,
                                              const float* __restrict__ bias,
                                              float* __restrict__ xp) {
    int tid = threadIdx.x;
    int wave = tid >> 6, lane = tid & 63;
    int quad = lane >> 4, l15 = lane & 15;
    int n0 = (blockIdx.x * 4 + wave) * 16;
    int n_a = n0 + l15;
    const float* xb = x + (n_a >> 10) * (CC * HW) + (n_a & (HW - 1));

    f32x4 acc[16];
#pragma unroll
    for (int i = 0; i < 16; i++) acc[i] = (f32x4){0.f, 0.f, 0.f, 0.f};

#pragma unroll
    for (int cc = 0; cc < 8; cc++) {
        bf16x8 ah, am, al;
#pragma unroll
        for (int j = 0; j < 8; j++) {
            float v = xb[(cc * 32 + quad * 8 + j) * HW];
            u16 h, m, l; split3(v, h, m, l);
            ah[j] = (short)h; am[j] = (short)m; al[j] = (short)l;
        }
#pragma unroll
        for (int dt = 0; dt < 16; dt++) {
            const float* wp = Wm + (dt * 16 + l15) * CC + cc * 32 + quad * 8;
            bf16x8 bh, bm, bl;
#pragma unroll
            for (int j = 0; j < 8; j++) {
                u16 h, m, l; split3(wp[j], h, m, l);
                bh[j] = (short)h; bm[j] = (short)m; bl[j] = (short)l;
            }
            acc[dt] = MFMA_BF16(ah, bh, acc[dt]);
            acc[dt] = MFMA_BF16(am, bh, acc[dt]);
            acc[dt] = MFMA_BF16(ah, bm, acc[dt]);
            acc[dt] = MFMA_BF16(al, bh, acc[dt]);
            acc[dt] = MFMA_BF16(am, bm, acc[dt]);
            acc[dt] = MFMA_BF16(ah, bl, acc[dt]);
        }
    }

#pragma unroll
    for (int dt = 0; dt < 16; dt++) {
        int d = dt * 16 + l15;          // C-layout: col = lane&15
        float bv = bias[d];
#pragma unroll
        for (int r = 0; r < 4; r++) {
            int n = n0 + quad * 4 + r;  // C-layout: row = quad*4 + reg
            xp[n * DD + d] = acc[dt][r] + bv;
        }
    }
}

// ---------------------------------------------------------------------------
// K2: approx distance GEMM + fused top-4 per (row, k-split) via packed keys.
// key = (u32)(score*32 + 4096) << 13 | k  (u32-sortable; ties -> lowest k).
// Grid (128 m-blocks, 8 k-splits). Block = 4 waves x 32 rows.
__global__ __launch_bounds__(256, 2) void k_dist(const float* __restrict__ xp,
                                                 const u16* __restrict__ cbTh,
                                                 const float* __restrict__ cbn,
                                                 u32* __restrict__ pkey) {
    __shared__ __align__(16) u16 tile[64 * 264];
    int tid = threadIdx.x, wave = tid >> 6, lane = tid & 63;
    int quad = lane >> 4, l15 = lane & 15;
    int n0 = blockIdx.x * 128 + wave * 32;
    int ksbase = blockIdx.y * (KK / 8);

    bf16x8 Ah[2][8];
#pragma unroll
    for (int mt = 0; mt < 2; mt++) {
        int n = n0 + mt * 16 + l15;
#pragma unroll
        for (int dc = 0; dc < 8; dc++) {
            const float* p = xp + n * DD + dc * 32 + quad * 8;
#pragma unroll
            for (int j = 0; j < 8; j++) Ah[mt][dc][j] = (short)f2b(p[j]);
        }
    }

    u32 key1[2][4], key2[2][4], key3[2][4], key4[2][4];
#pragma unroll
    for (int mt = 0; mt < 2; mt++)
#pragma unroll
        for (int r = 0; r < 4; r++) {
            key1[mt][r] = 0xffffffffu; key2[mt][r] = 0xffffffffu;
            key3[mt][r] = 0xffffffffu; key4[mt][r] = 0xffffffffu;
        }

    for (int kc = 0; kc < 16; kc++) {
        int kglob = ksbase + kc * 64;
        __syncthreads();
#pragma unroll
        for (int it = 0; it < 8; it++) {
            int lin = it * 256 + tid;       // 2048 chunks of 16B
            int row = lin >> 5, c16 = lin & 31;
            bf16x8 v = *(const bf16x8*)(cbTh + (kglob + row) * DD + c16 * 8);
            *(bf16x8*)(tile + row * 264 + c16 * 8) = v;
        }
        __syncthreads();
#pragma unroll
        for (int kt = 0; kt < 4; kt++) {
            int klocal = kt * 16 + l15;     // B-frag col = lane&15
            bf16x8 Bf[8];
#pragma unroll
            for (int dc = 0; dc < 8; dc++)
                Bf[dc] = *(const bf16x8*)(tile + klocal * 264 + dc * 32 + quad * 8);
            f32x4 a0 = (f32x4){0.f, 0.f, 0.f, 0.f};
            f32x4 a1 = (f32x4){0.f, 0.f, 0.f, 0.f};
#pragma unroll
            for (int dc = 0; dc < 8; dc++) {
                a0 = MFMA_BF16(Ah[0][dc], Bf[dc], a0);
                a1 = MFMA_BF16(Ah[1][dc], Bf[dc], a1);
            }
            u32 kg = (u32)(kglob + klocal);
            float cb2 = cbn[kg];
#pragma unroll
            for (int mt = 0; mt < 2; mt++) {
                f32x4 a = mt ? a1 : a0;
#pragma unroll
                for (int r = 0; r < 4; r++) {
                    float s = cb2 - 2.f * a[r];
                    u32 q = (u32)(s * 32.f + 4096.f);
                    u32 key = (q << 13) | kg;
                    u32 t1 = min(key, key1[mt][r]); u32 u1 = max(key, key1[mt][r]);
                    key1[mt][r] = t1;
                    u32 t2 = min(u1, key2[mt][r]);  u32 u2 = max(u1, key2[mt][r]);
                    key2[mt][r] = t2;
                    u32 t3 = min(u2, key3[mt][r]);  u32 u3 = max(u2, key3[mt][r]);
                    key3[mt][r] = t3;
                    key4[mt][r] = min(u3, key4[mt][r]);
                }
            }
        }
    }

#pragma unroll
    for (int mt = 0; mt < 2; mt++) {
#pragma unroll
        for (int r = 0; r < 4; r++) {
            u32 k1 = key1[mt][r], k2 = key2[mt][r], k3 = key3[mt][r], k4 = key4[mt][r];
#pragma unroll
            for (int m = 1; m < 16; m <<= 1) {
                u32 o[4];
                o[0] = (u32)__shfl_xor((int)k1, m, 64);
                o[1] = (u32)__shfl_xor((int)k2, m, 64);
                o[2] = (u32)__shfl_xor((int)k3, m, 64);
                o[3] = (u32)__shfl_xor((int)k4, m, 64);
#pragma unroll
                for (int j = 0; j < 4; j++) {
                    u32 t1 = min(o[j], k1); u32 u1 = max(o[j], k1); k1 = t1;
                    u32 t2 = min(u1, k2);   u32 u2 = max(u1, k2);   k2 = t2;
                    u32 t3 = min(u2, k3);   u32 u3 = max(u2, k3);   k3 = t3;
                    k4 = min(u3, k4);
                }
            }
            if (l15 == 0) {
                int n = n0 + mt * 16 + quad * 4 + r;
                int base = (n * 8 + blockIdx.y) * 4;
                pkey[base] = k1; pkey[base + 1] = k2;
                pkey[base + 2] = k3; pkey[base + 3] = k4;
            }
        }
    }
}

// ---------------------------------------------------------------------------
// K3: exact fp64 rescore of 32 candidates per row. One wave per row.
// Writes idxv (ws) and the fp32 index value into the indices chunk of d_out.
__global__ __launch_bounds__(256) void k_rescore(const float* __restrict__ xp,
                                                 const float* __restrict__ cbT,
                                                 const u32* __restrict__ pkey,
                                                 u32* __restrict__ idxv,
                                                 float* __restrict__ outIdx,
                                                 float* __restrict__ scal) {
    int tid = threadIdx.x, wave = tid >> 6, lane = tid & 63;
    int n = blockIdx.x * 4 + wave;
    f32x4 xv = *(const f32x4*)(xp + n * DD + lane * 4);

    double bestv = 1e300;
    u32 besti = 0u;
#pragma unroll
    for (int j = 0; j < 32; j++) {
        u32 kg = pkey[n * 32 + j] & 8191u;
        f32x4 cv = *(const f32x4*)(cbT + kg * DD + lane * 4);
        double s = 0.0;
#pragma unroll
        for (int t = 0; t < 4; t++) {
            double d = (double)xv[t] - (double)cv[t];
            s += d * d;
        }
#pragma unroll
        for (int m = 1; m < 64; m <<= 1) s += __shfl_xor(s, m, 64);
        if (s < bestv || (s == bestv && kg < besti)) { bestv = s; besti = kg; }
    }
    if (lane == 0) {
        idxv[n] = besti & 8191u;
        outIdx[n] = (float)besti;          // fp32 output element
        atomicAdd(&scal[0], (float)bestv);
    }
}

// ---------------------------------------------------------------------------
// K4: gather quantized (B,D,H,W) fp32: out0[tid] = cbT[idx[n]*256 + d].
// Rewrites ALL of d_out chunk 0 (including the cbTh/pkey scratch bytes).
__global__ __launch_bounds__(256) void k_gather(const float* __restrict__ cbT,
                                                const u32* __restrict__ idxv,
                                                float* __restrict__ out0) {
    int tid = blockIdx.x * 256 + threadIdx.x;
    int d = (tid >> 10) & 255;
    int n = ((tid >> 18) << 10) | (tid & 1023);
    u32 k = idxv[n] & 8191u;
    out0[tid] = cbT[k * DD + d];
}

// ---------------------------------------------------------------------------
// K5: diff = sum min||xp-c||^2 / (N*D), fp32 output element.
__global__ void k_final(const float* __restrict__ scal, float* __restrict__ out) {
    out[0] = scal[0] * (1.f / (float)OUT0);
}

// ---------------------------------------------------------------------------
extern "C" void kernel_launch(void* const* d_in, const int* in_sizes, int n_in,
                              void* d_out, int out_size, void* d_ws, size_t ws_size,
                              hipStream_t stream) {
    // Identify inputs by element count (all four are distinct sizes).
    const float* x = nullptr; const float* Wm = nullptr;
    const float* bias = nullptr; const float* cb = nullptr;
    for (int i = 0; i < n_in; i++) {
        switch (in_sizes[i]) {
            case 4194304: x    = (const float*)d_in[i]; break;  // (16,256,32,32)
            case 65536:   Wm   = (const float*)d_in[i]; break;  // (256,256)
            case 256:     bias = (const float*)d_in[i]; break;  // (256,)
            case 2097152: cb   = (const float*)d_in[i]; break;  // (256,8192)
        }
    }

    // d_out is FP32: [quantized (4194304) | diff (1) | indices (16384)]
    float* out0    = (float*)d_out;
    float* outDiff = (float*)d_out + OUT0;
    float* outIdx  = (float*)d_out + OUT0 + 1;

    // Transient scratch inside d_out chunk 0 (16.7 MB; fully rewritten by
    // k_gather before the harness reads):
    u16* cbTh = (u16*)d_out;                          // 4 MB  (K,D) bf16
    u32* pkey = (u32*)((char*)d_out + 4194304);       // 2 MB  candidate keys

    // Workspace (24.3 MB):
    char* w = (char*)d_ws;
    float* cbT  = (float*)(w);                        // 8 MB  (K,D) fp32
    float* xp   = (float*)(w + 8388608);              // 16 MB (N,D) fp32
    float* cbn  = (float*)(w + 25165824);             // 32 KB
    u32*   idxv = (u32*)(w + 25198592);               // 64 KB
    float* scal = (float*)(w + 25264128);             // 16 B

    k_canon<<<dim3(KK / 32, DD / 32), dim3(32, 8), 0, stream>>>(cb, cbT, cbTh);
    k_cbnorm<<<KK / 256, 256, 0, stream>>>(cb, cbn, scal);
    k_proj<<<NN / 64, 256, 0, stream>>>(x, Wm, bias, xp);
    k_dist<<<dim3(NN / 128, 8), 256, 0, stream>>>(xp, cbTh, cbn, pkey);
    k_rescore<<<NN / 4, 256, 0, stream>>>(xp, cbT, pkey, idxv, outIdx, scal);
    k_gather<<<OUT0 / 256, 256, 0, stream>>>(cbT, idxv, out0);
    k_final<<<1, 1, 0, stream>>>(scal, outDiff);
}

// Round 5
// 361.116 us; speedup vs baseline: 1.5114x; 1.5114x over previous
//
#include <hip/hip_runtime.h>

typedef short bf16x8 __attribute__((ext_vector_type(8)));
typedef float f32x4 __attribute__((ext_vector_type(4)));
using u16 = unsigned short;
using u32 = unsigned int;

#define MFMA_BF16(A, B, C) __builtin_amdgcn_mfma_f32_16x16x32_bf16((A), (B), (C), 0, 0, 0)

#define CC 256
#define DD 256
#define KK 8192
#define NN 16384     // B*H*W
#define HW 1024      // H*W
#define OUT0 4194304 // B*D*H*W

static __device__ __forceinline__ float b2f(u16 u) {
    union { u32 i; float f; } v; v.i = ((u32)u) << 16; return v.f;
}
static __device__ __forceinline__ u16 f2b(float f) {  // RNE fp32 -> bf16
    union { float f; u32 i; } v; v.f = f;
    u32 x = v.i;
    u32 r = (x + 0x7fffu + ((x >> 16) & 1u)) >> 16;
    return (u16)r;
}
static __device__ __forceinline__ void split3(float v, u16& h, u16& m, u16& l) {
    h = f2b(v); float r1 = v - b2f(h);
    m = f2b(r1); float r2 = r1 - b2f(m);
    l = f2b(r2);
}

// ---------------------------------------------------------------------------
// K0a: transpose codebook (D,K) fp32 -> cbT (K,D) fp32 (ws) + cbTh (K,D) bf16.
// cbTh lives in d_out chunk-0 scratch (rewritten by k_gather at the end).
__global__ __launch_bounds__(256) void k_canon(const float* __restrict__ cb,
                                               float* __restrict__ cbT,
                                               u16* __restrict__ cbTh) {
    __shared__ float tile[32][33];
    int k0 = blockIdx.x * 32, d0 = blockIdx.y * 32;
    int tx = threadIdx.x, ty = threadIdx.y;  // 32 x 8
#pragma unroll
    for (int i = 0; i < 4; i++) {
        int d = d0 + ty + i * 8;
        tile[ty + i * 8][tx] = cb[d * KK + k0 + tx];
    }
    __syncthreads();
#pragma unroll
    for (int i = 0; i < 4; i++) {
        int k = k0 + ty + i * 8;
        float v = tile[tx][ty + i * 8];
        cbT[k * DD + d0 + tx] = v;
        cbTh[k * DD + d0 + tx] = f2b(v);
    }
}

// ---------------------------------------------------------------------------
// K0b: cbn[k] = sum_d cb[d,k]^2 (fp32; approx scores only).
__global__ __launch_bounds__(256) void k_cbnorm(const float* __restrict__ cb,
                                                float* __restrict__ cbn) {
    int k = blockIdx.x * 256 + threadIdx.x;
    float s = 0.f;
    for (int d = 0; d < DD; d++) {
        float v = cb[d * KK + k];
        s += v * v;
    }
    cbn[k] = s;
}

// ---------------------------------------------------------------------------
// K0c: split conv_w (D,C) fp32 -> 3-way bf16 (hi/mid/lo), precomputed once.
__global__ __launch_bounds__(256) void k_wsplit(const float* __restrict__ Wm,
                                                u16* __restrict__ wh,
                                                u16* __restrict__ wm,
                                                u16* __restrict__ wl) {
    int t = blockIdx.x * 256 + threadIdx.x;
    u16 h, m, l; split3(Wm[t], h, m, l);
    wh[t] = h; wm[t] = m; wl[t] = l;
}

// ---------------------------------------------------------------------------
// K1: xp = x_r @ W^T + b via bf16x3 split MFMA (6 terms ~ fp32 accuracy).
// W-split preloaded as bf16x8; A split on the fly. One wave per 16 rows.
__global__ __launch_bounds__(256) void k_proj(const float* __restrict__ x,
                                              const u16* __restrict__ wh,
                                              const u16* __restrict__ wm,
                                              const u16* __restrict__ wl,
                                              const float* __restrict__ bias,
                                              float* __restrict__ xp) {
    int tid = threadIdx.x;
    int wave = tid >> 6, lane = tid & 63;
    int quad = lane >> 4, l15 = lane & 15;
    int n0 = (blockIdx.x * 4 + wave) * 16;
    int n_a = n0 + l15;
    const float* xb = x + (n_a >> 10) * (CC * HW) + (n_a & (HW - 1));

    f32x4 acc[16];
#pragma unroll
    for (int i = 0; i < 16; i++) acc[i] = (f32x4){0.f, 0.f, 0.f, 0.f};

#pragma unroll
    for (int cc = 0; cc < 8; cc++) {
        bf16x8 ah, am, al;
#pragma unroll
        for (int j = 0; j < 8; j++) {
            float v = xb[(cc * 32 + quad * 8 + j) * HW];
            u16 h, m, l; split3(v, h, m, l);
            ah[j] = (short)h; am[j] = (short)m; al[j] = (short)l;
        }
#pragma unroll
        for (int dt = 0; dt < 16; dt++) {
            int off = (dt * 16 + l15) * CC + cc * 32 + quad * 8;
            const bf16x8 bh = *(const bf16x8*)(wh + off);
            const bf16x8 bm = *(const bf16x8*)(wm + off);
            const bf16x8 bl = *(const bf16x8*)(wl + off);
            acc[dt] = MFMA_BF16(ah, bh, acc[dt]);
            acc[dt] = MFMA_BF16(am, bh, acc[dt]);
            acc[dt] = MFMA_BF16(ah, bm, acc[dt]);
            acc[dt] = MFMA_BF16(al, bh, acc[dt]);
            acc[dt] = MFMA_BF16(am, bm, acc[dt]);
            acc[dt] = MFMA_BF16(ah, bl, acc[dt]);
        }
    }

#pragma unroll
    for (int dt = 0; dt < 16; dt++) {
        int d = dt * 16 + l15;          // C-layout: col = lane&15
        float bv = bias[d];
#pragma unroll
        for (int r = 0; r < 4; r++) {
            int n = n0 + quad * 4 + r;  // C-layout: row = quad*4 + reg
            xp[n * DD + d] = acc[dt][r] + bv;
        }
    }
}

// ---------------------------------------------------------------------------
// K2: approx distance GEMM + fused top-4 per (row, k-split) via packed keys.
// key = (u32)(score*32 + 4096) << 13 | k  (u32-sortable; ties -> lowest k).
// Grid (128 m-blocks, 8 k-splits). Block = 4 waves x 32 rows.
__global__ __launch_bounds__(256, 2) void k_dist(const float* __restrict__ xp,
                                                 const u16* __restrict__ cbTh,
                                                 const float* __restrict__ cbn,
                                                 u32* __restrict__ pkey) {
    __shared__ __align__(16) u16 tile[64 * 264];
    int tid = threadIdx.x, wave = tid >> 6, lane = tid & 63;
    int quad = lane >> 4, l15 = lane & 15;
    int n0 = blockIdx.x * 128 + wave * 32;
    int ksbase = blockIdx.y * (KK / 8);

    bf16x8 Ah[2][8];
#pragma unroll
    for (int mt = 0; mt < 2; mt++) {
        int n = n0 + mt * 16 + l15;
#pragma unroll
        for (int dc = 0; dc < 8; dc++) {
            const float* p = xp + n * DD + dc * 32 + quad * 8;
#pragma unroll
            for (int j = 0; j < 8; j++) Ah[mt][dc][j] = (short)f2b(p[j]);
        }
    }

    u32 key1[2][4], key2[2][4], key3[2][4], key4[2][4];
#pragma unroll
    for (int mt = 0; mt < 2; mt++)
#pragma unroll
        for (int r = 0; r < 4; r++) {
            key1[mt][r] = 0xffffffffu; key2[mt][r] = 0xffffffffu;
            key3[mt][r] = 0xffffffffu; key4[mt][r] = 0xffffffffu;
        }

    for (int kc = 0; kc < 16; kc++) {
        int kglob = ksbase + kc * 64;
        __syncthreads();
#pragma unroll
        for (int it = 0; it < 8; it++) {
            int lin = it * 256 + tid;       // 2048 chunks of 16B
            int row = lin >> 5, c16 = lin & 31;
            bf16x8 v = *(const bf16x8*)(cbTh + (kglob + row) * DD + c16 * 8);
            *(bf16x8*)(tile + row * 264 + c16 * 8) = v;
        }
        __syncthreads();
#pragma unroll
        for (int kt = 0; kt < 4; kt++) {
            int klocal = kt * 16 + l15;     // B-frag col = lane&15
            bf16x8 Bf[8];
#pragma unroll
            for (int dc = 0; dc < 8; dc++)
                Bf[dc] = *(const bf16x8*)(tile + klocal * 264 + dc * 32 + quad * 8);
            f32x4 a0 = (f32x4){0.f, 0.f, 0.f, 0.f};
            f32x4 a1 = (f32x4){0.f, 0.f, 0.f, 0.f};
#pragma unroll
            for (int dc = 0; dc < 8; dc++) {
                a0 = MFMA_BF16(Ah[0][dc], Bf[dc], a0);
                a1 = MFMA_BF16(Ah[1][dc], Bf[dc], a1);
            }
            u32 kg = (u32)(kglob + klocal);
            float cb2 = cbn[kg];
#pragma unroll
            for (int mt = 0; mt < 2; mt++) {
                f32x4 a = mt ? a1 : a0;
#pragma unroll
                for (int r = 0; r < 4; r++) {
                    float s = cb2 - 2.f * a[r];
                    u32 q = (u32)(s * 32.f + 4096.f);
                    u32 key = (q << 13) | kg;
                    u32 t1 = min(key, key1[mt][r]); u32 u1 = max(key, key1[mt][r]);
                    key1[mt][r] = t1;
                    u32 t2 = min(u1, key2[mt][r]);  u32 u2 = max(u1, key2[mt][r]);
                    key2[mt][r] = t2;
                    u32 t3 = min(u2, key3[mt][r]);  u32 u3 = max(u2, key3[mt][r]);
                    key3[mt][r] = t3;
                    key4[mt][r] = min(u3, key4[mt][r]);
                }
            }
        }
    }

#pragma unroll
    for (int mt = 0; mt < 2; mt++) {
#pragma unroll
        for (int r = 0; r < 4; r++) {
            u32 k1 = key1[mt][r], k2 = key2[mt][r], k3 = key3[mt][r], k4 = key4[mt][r];
#pragma unroll
            for (int m = 1; m < 16; m <<= 1) {
                u32 o[4];
                o[0] = (u32)__shfl_xor((int)k1, m, 64);
                o[1] = (u32)__shfl_xor((int)k2, m, 64);
                o[2] = (u32)__shfl_xor((int)k3, m, 64);
                o[3] = (u32)__shfl_xor((int)k4, m, 64);
#pragma unroll
                for (int j = 0; j < 4; j++) {
                    u32 t1 = min(o[j], k1); u32 u1 = max(o[j], k1); k1 = t1;
                    u32 t2 = min(u1, k2);   u32 u2 = max(u1, k2);   k2 = t2;
                    u32 t3 = min(u2, k3);   u32 u3 = max(u2, k3);   k3 = t3;
                    k4 = min(u3, k4);
                }
            }
            if (l15 == 0) {
                int n = n0 + mt * 16 + quad * 4 + r;
                int base = (n * 8 + blockIdx.y) * 4;
                pkey[base] = k1; pkey[base + 1] = k2;
                pkey[base + 2] = k3; pkey[base + 3] = k4;
            }
        }
    }
}

// ---------------------------------------------------------------------------
// K3: exact fp64 rescore of 32 candidates per row. One wave per row.
// Lane = (sub=lane>>3: candidate-in-group) x (oct=lane&7: 32-dim chunk).
// Per group of 8 candidates: 3 shared butterfly steps; 3 final steps across
// candidates. 15 shuffles total (vs 192 in the serial form).
__global__ __launch_bounds__(256) void k_rescore(const float* __restrict__ xp,
                                                 const float* __restrict__ cbT,
                                                 const u32* __restrict__ pkey,
                                                 u32* __restrict__ idxv,
                                                 float* __restrict__ outIdx,
                                                 float* __restrict__ pmin) {
    int tid = threadIdx.x, wave = tid >> 6, lane = tid & 63;
    int n = blockIdx.x * 4 + wave;
    int sub = lane >> 3;   // candidate selector within group
    int oct = lane & 7;    // dim-chunk selector (32 dims)

    f32x4 xv[8];
    const float* xb = xp + n * DD + oct * 32;
#pragma unroll
    for (int t = 0; t < 8; t++) xv[t] = *(const f32x4*)(xb + t * 4);

    u32 myk = pkey[n * 32 + (lane & 31)] & 8191u;

    double bestv = 1e300;
    u32 besti = 0u;
#pragma unroll
    for (int g = 0; g < 4; g++) {
        int c = g * 8 + sub;
        u32 kg = (u32)__shfl((int)myk, c, 64);
        const float* cv = cbT + kg * DD + oct * 32;
        double s = 0.0;
#pragma unroll
        for (int t = 0; t < 8; t++) {
            f32x4 cvv = *(const f32x4*)(cv + t * 4);
#pragma unroll
            for (int q = 0; q < 4; q++) {
                double d = (double)xv[t][q] - (double)cvv[q];
                s += d * d;
            }
        }
        s += __shfl_xor(s, 1, 64);
        s += __shfl_xor(s, 2, 64);
        s += __shfl_xor(s, 4, 64);
        if (s < bestv || (s == bestv && kg < besti)) { bestv = s; besti = kg; }
    }
#pragma unroll
    for (int m = 8; m < 64; m <<= 1) {
        double ov = __shfl_xor(bestv, m, 64);
        u32 oi = (u32)__shfl_xor((int)besti, m, 64);
        if (ov < bestv || (ov == bestv && oi < besti)) { bestv = ov; besti = oi; }
    }
    if (lane == 0) {
        idxv[n] = besti;
        outIdx[n] = (float)besti;
        pmin[n] = (float)bestv;
    }
}

// ---------------------------------------------------------------------------
// K4: diff = sum(pmin)/(N*D), fp64 accumulate. MUST run before k_gather
// (pmin lives in d_out chunk-0 scratch). One block of 1024 threads.
__global__ __launch_bounds__(1024) void k_final(const float* __restrict__ pmin,
                                                float* __restrict__ out) {
    __shared__ double sm[16];
    int tid = threadIdx.x, lane = tid & 63, wv = tid >> 6;
    double s = 0.0;
#pragma unroll
    for (int i = 0; i < 16; i++) s += (double)pmin[i * 1024 + tid];
#pragma unroll
    for (int m = 1; m < 64; m <<= 1) s += __shfl_xor(s, m, 64);
    if (lane == 0) sm[wv] = s;
    __syncthreads();
    if (tid == 0) {
        double t = 0.0;
#pragma unroll
        for (int i = 0; i < 16; i++) t += sm[i];
        out[0] = (float)(t * (1.0 / (double)OUT0));
    }
}

// ---------------------------------------------------------------------------
// K5: gather quantized (B,D,H,W) fp32: out0[tid] = cbT[idx[n]*256 + d].
// Rewrites ALL of d_out chunk 0 (including every scratch byte).
__global__ __launch_bounds__(256) void k_gather(const float* __restrict__ cbT,
                                                const u32* __restrict__ idxv,
                                                float* __restrict__ out0) {
    int tid = blockIdx.x * 256 + threadIdx.x;
    int d = (tid >> 10) & 255;
    int n = ((tid >> 18) << 10) | (tid & 1023);
    u32 k = idxv[n] & 8191u;
    out0[tid] = cbT[k * DD + d];
}

// ---------------------------------------------------------------------------
extern "C" void kernel_launch(void* const* d_in, const int* in_sizes, int n_in,
                              void* d_out, int out_size, void* d_ws, size_t ws_size,
                              hipStream_t stream) {
    // Identify inputs by element count (all four are distinct sizes).
    const float* x = nullptr; const float* Wm = nullptr;
    const float* bias = nullptr; const float* cb = nullptr;
    for (int i = 0; i < n_in; i++) {
        switch (in_sizes[i]) {
            case 4194304: x    = (const float*)d_in[i]; break;  // (16,256,32,32)
            case 65536:   Wm   = (const float*)d_in[i]; break;  // (256,256)
            case 256:     bias = (const float*)d_in[i]; break;  // (256,)
            case 2097152: cb   = (const float*)d_in[i]; break;  // (256,8192)
        }
    }

    // d_out is FP32: [quantized (4194304) | diff (1) | indices (16384)]
    float* out0    = (float*)d_out;
    float* outDiff = (float*)d_out + OUT0;
    float* outIdx  = (float*)d_out + OUT0 + 1;

    // Transient scratch inside d_out chunk 0 (16.7 MB fp32 region; every
    // byte rewritten by k_gather before the harness reads):
    char* o = (char*)d_out;
    u16*   cbTh = (u16*)o;                       // [0, 4 MB)
    u32*   pkey = (u32*)(o + 4194304);           // [4 MB, 6 MB)
    u16*   wh   = (u16*)(o + 6291456);           // 128 KB
    u16*   wm   = (u16*)(o + 6422528);           // 128 KB
    u16*   wl   = (u16*)(o + 6553600);           // 128 KB
    float* pmin = (float*)(o + 6684672);         // 64 KB   (read by k_final BEFORE k_gather)

    // Workspace (same 25.26 MB footprint that passed in round 4):
    char* w = (char*)d_ws;
    float* cbT  = (float*)(w);                   // 8 MB  (K,D) fp32
    float* xp   = (float*)(w + 8388608);         // 16 MB (N,D) fp32
    float* cbn  = (float*)(w + 25165824);        // 32 KB
    u32*   idxv = (u32*)(w + 25198592);          // 64 KB

    k_canon<<<dim3(KK / 32, DD / 32), dim3(32, 8), 0, stream>>>(cb, cbT, cbTh);
    k_cbnorm<<<KK / 256, 256, 0, stream>>>(cb, cbn);
    k_wsplit<<<(DD * CC) / 256, 256, 0, stream>>>(Wm, wh, wm, wl);
    k_proj<<<NN / 64, 256, 0, stream>>>(x, wh, wm, wl, bias, xp);
    k_dist<<<dim3(NN / 128, 8), 256, 0, stream>>>(xp, cbTh, cbn, pkey);
    k_rescore<<<NN / 4, 256, 0, stream>>>(xp, cbT, pkey, idxv, outIdx, pmin);
    k_final<<<1, 1024, 0, stream>>>(pmin, outDiff);
    k_gather<<<OUT0 / 256, 256, 0, stream>>>(cbT, idxv, out0);
}

// Round 6
// 345.696 us; speedup vs baseline: 1.5788x; 1.0446x over previous
//
#include <hip/hip_runtime.h>

typedef short bf16x8 __attribute__((ext_vector_type(8)));
typedef float f32x4 __attribute__((ext_vector_type(4)));
using u16 = unsigned short;
using u32 = unsigned int;

#define MFMA_BF16(A, B, C) __builtin_amdgcn_mfma_f32_16x16x32_bf16((A), (B), (C), 0, 0, 0)

#define CC 256
#define DD 256
#define KK 8192
#define NN 16384     // B*H*W
#define HW 1024      // H*W
#define OUT0 4194304 // B*D*H*W
#define KSPLIT 16
#define KROWS 32     // k-rows per LDS tile

static __device__ __forceinline__ float b2f(u16 u) {
    union { u32 i; float f; } v; v.i = ((u32)u) << 16; return v.f;
}
static __device__ __forceinline__ u16 f2b(float f) {  // RNE fp32 -> bf16
    union { float f; u32 i; } v; v.f = f;
    u32 x = v.i;
    u32 r = (x + 0x7fffu + ((x >> 16) & 1u)) >> 16;
    return (u16)r;
}
static __device__ __forceinline__ void split3(float v, u16& h, u16& m, u16& l) {
    h = f2b(v); float r1 = v - b2f(h);
    m = f2b(r1); float r2 = r1 - b2f(m);
    l = f2b(r2);
}

// ---------------------------------------------------------------------------
// K0a: transpose codebook (D,K) fp32 -> cbT (K,D) fp32 (ws) + cbTh (K,D) bf16.
__global__ __launch_bounds__(256) void k_canon(const float* __restrict__ cb,
                                               float* __restrict__ cbT,
                                               u16* __restrict__ cbTh) {
    __shared__ float tile[32][33];
    int k0 = blockIdx.x * 32, d0 = blockIdx.y * 32;
    int tx = threadIdx.x, ty = threadIdx.y;  // 32 x 8
#pragma unroll
    for (int i = 0; i < 4; i++) {
        int d = d0 + ty + i * 8;
        tile[ty + i * 8][tx] = cb[d * KK + k0 + tx];
    }
    __syncthreads();
#pragma unroll
    for (int i = 0; i < 4; i++) {
        int k = k0 + ty + i * 8;
        float v = tile[tx][ty + i * 8];
        cbT[k * DD + d0 + tx] = v;
        cbTh[k * DD + d0 + tx] = f2b(v);
    }
}

// ---------------------------------------------------------------------------
// K0b: cbnq[k] = 32*sum_d cb[d,k]^2 + 4096 (pre-scaled for the packed key).
__global__ __launch_bounds__(256) void k_cbnorm(const float* __restrict__ cb,
                                                float* __restrict__ cbnq) {
    int k = blockIdx.x * 256 + threadIdx.x;
    float s = 0.f;
    for (int d = 0; d < DD; d++) {
        float v = cb[d * KK + k];
        s += v * v;
    }
    cbnq[k] = 32.f * s + 4096.f;
}

// ---------------------------------------------------------------------------
// K0c: split conv_w (D,C) fp32 -> 3-way bf16 (hi/mid/lo), precomputed once.
__global__ __launch_bounds__(256) void k_wsplit(const float* __restrict__ Wm,
                                                u16* __restrict__ wh,
                                                u16* __restrict__ wm,
                                                u16* __restrict__ wl) {
    int t = blockIdx.x * 256 + threadIdx.x;
    u16 h, m, l; split3(Wm[t], h, m, l);
    wh[t] = h; wm[t] = m; wl[t] = l;
}

// ---------------------------------------------------------------------------
// K1: xp = x_r @ W^T + b via bf16x3 split MFMA (6 terms ~ fp32 accuracy).
__global__ __launch_bounds__(256) void k_proj(const float* __restrict__ x,
                                              const u16* __restrict__ wh,
                                              const u16* __restrict__ wm,
                                              const u16* __restrict__ wl,
                                              const float* __restrict__ bias,
                                              float* __restrict__ xp) {
    int tid = threadIdx.x;
    int wave = tid >> 6, lane = tid & 63;
    int quad = lane >> 4, l15 = lane & 15;
    int n0 = (blockIdx.x * 4 + wave) * 16;
    int n_a = n0 + l15;
    const float* xb = x + (n_a >> 10) * (CC * HW) + (n_a & (HW - 1));

    f32x4 acc[16];
#pragma unroll
    for (int i = 0; i < 16; i++) acc[i] = (f32x4){0.f, 0.f, 0.f, 0.f};

#pragma unroll
    for (int cc = 0; cc < 8; cc++) {
        bf16x8 ah, am, al;
#pragma unroll
        for (int j = 0; j < 8; j++) {
            float v = xb[(cc * 32 + quad * 8 + j) * HW];
            u16 h, m, l; split3(v, h, m, l);
            ah[j] = (short)h; am[j] = (short)m; al[j] = (short)l;
        }
#pragma unroll
        for (int dt = 0; dt < 16; dt++) {
            int off = (dt * 16 + l15) * CC + cc * 32 + quad * 8;
            const bf16x8 bh = *(const bf16x8*)(wh + off);
            const bf16x8 bm = *(const bf16x8*)(wm + off);
            const bf16x8 bl = *(const bf16x8*)(wl + off);
            acc[dt] = MFMA_BF16(ah, bh, acc[dt]);
            acc[dt] = MFMA_BF16(am, bh, acc[dt]);
            acc[dt] = MFMA_BF16(ah, bm, acc[dt]);
            acc[dt] = MFMA_BF16(al, bh, acc[dt]);
            acc[dt] = MFMA_BF16(am, bm, acc[dt]);
            acc[dt] = MFMA_BF16(ah, bl, acc[dt]);
        }
    }

#pragma unroll
    for (int dt = 0; dt < 16; dt++) {
        int d = dt * 16 + l15;          // C-layout: col = lane&15
        float bv = bias[d];
#pragma unroll
        for (int r = 0; r < 4; r++) {
            int n = n0 + quad * 4 + r;  // C-layout: row = quad*4 + reg
            xp[n * DD + d] = acc[dt][r] + bv;
        }
    }
}

// ---------------------------------------------------------------------------
// K2: approx distance GEMM + fused top-2 per (row-slot, lane) via packed keys.
// key = (u32)(cbnq[k] - 64*dot) << 13 | k   (u32-sortable; ties -> lowest k).
// Grid (128 m-blocks, 16 k-splits). Block = 4 waves x 32 rows. LDS 16.9 KB.
__global__ __launch_bounds__(256) void k_dist(const float* __restrict__ xp,
                                              const u16* __restrict__ cbTh,
                                              const float* __restrict__ cbnq,
                                              u32* __restrict__ pkey) {
    __shared__ __align__(16) u16 tile[KROWS * 264];
    int tid = threadIdx.x, wave = tid >> 6, lane = tid & 63;
    int quad = lane >> 4, l15 = lane & 15;
    int n0 = blockIdx.x * 128 + wave * 32;
    int ksbase = blockIdx.y * (KK / KSPLIT);   // 512 codes per split

    bf16x8 Ah[2][8];
#pragma unroll
    for (int mt = 0; mt < 2; mt++) {
        int n = n0 + mt * 16 + l15;
#pragma unroll
        for (int dc = 0; dc < 8; dc++) {
            const float* p = xp + n * DD + dc * 32 + quad * 8;
#pragma unroll
            for (int j = 0; j < 8; j++) Ah[mt][dc][j] = (short)f2b(p[j]);
        }
    }

    u32 key1[2][4], key2[2][4];
#pragma unroll
    for (int mt = 0; mt < 2; mt++)
#pragma unroll
        for (int r = 0; r < 4; r++) { key1[mt][r] = 0xffffffffu; key2[mt][r] = 0xffffffffu; }

    for (int kc = 0; kc < 16; kc++) {
        int kglob = ksbase + kc * KROWS;
        __syncthreads();
        // stage 32 rows x 256 u16 (1024 x 16B chunks, 4 per thread)
#pragma unroll
        for (int it = 0; it < 4; it++) {
            int lin = it * 256 + tid;
            int row = lin >> 5, c16 = lin & 31;
            bf16x8 v = *(const bf16x8*)(cbTh + (kglob + row) * DD + c16 * 8);
            *(bf16x8*)(tile + row * 264 + c16 * 8) = v;
        }
        __syncthreads();
#pragma unroll
        for (int kt = 0; kt < 2; kt++) {
            int klocal = kt * 16 + l15;
            bf16x8 Bf[8];
#pragma unroll
            for (int dc = 0; dc < 8; dc++)
                Bf[dc] = *(const bf16x8*)(tile + klocal * 264 + dc * 32 + quad * 8);
            f32x4 a0 = (f32x4){0.f, 0.f, 0.f, 0.f};
            f32x4 a1 = (f32x4){0.f, 0.f, 0.f, 0.f};
#pragma unroll
            for (int dc = 0; dc < 8; dc++) {
                a0 = MFMA_BF16(Ah[0][dc], Bf[dc], a0);
                a1 = MFMA_BF16(Ah[1][dc], Bf[dc], a1);
            }
            u32 kg = (u32)(kglob + klocal);
            float cq = cbnq[kg];
#pragma unroll
            for (int mt = 0; mt < 2; mt++) {
                f32x4 a = mt ? a1 : a0;
#pragma unroll
                for (int r = 0; r < 4; r++) {
                    // 6 VALU per score: fma, cvt, lshl_add, min, max, min
                    u32 q = (u32)fmaf(a[r], -64.f, cq);
                    u32 key = (q << 13) | kg;
                    u32 t1 = min(key, key1[mt][r]);
                    u32 u1 = max(key, key1[mt][r]);
                    key1[mt][r] = t1;
                    key2[mt][r] = min(u1, key2[mt][r]);
                }
            }
        }
    }

    // merge top-2 across the 16 lanes (l15 groups) sharing the same C rows
#pragma unroll
    for (int mt = 0; mt < 2; mt++) {
#pragma unroll
        for (int r = 0; r < 4; r++) {
            u32 k1 = key1[mt][r], k2 = key2[mt][r];
#pragma unroll
            for (int m = 1; m < 16; m <<= 1) {
                u32 o1 = (u32)__shfl_xor((int)k1, m, 64);
                u32 o2 = (u32)__shfl_xor((int)k2, m, 64);
                u32 m1 = min(k1, o1);
                u32 M1 = max(k1, o1);
                k1 = m1;
                k2 = min(M1, min(k2, o2));
            }
            if (l15 == 0) {
                int n = n0 + mt * 16 + quad * 4 + r;
                int base = (n * KSPLIT + blockIdx.y) * 2;
                pkey[base] = k1; pkey[base + 1] = k2;
            }
        }
    }
}

// ---------------------------------------------------------------------------
// K3: exact fp64 rescore of 32 candidates per row. One wave per row.
// Lane = (sub=lane>>3: candidate) x (oct=lane&7: 32-dim chunk).
__global__ __launch_bounds__(256) void k_rescore(const float* __restrict__ xp,
                                                 const float* __restrict__ cbT,
                                                 const u32* __restrict__ pkey,
                                                 u32* __restrict__ idxv,
                                                 float* __restrict__ outIdx,
                                                 float* __restrict__ pmin) {
    int tid = threadIdx.x, wave = tid >> 6, lane = tid & 63;
    int n = blockIdx.x * 4 + wave;
    int sub = lane >> 3;
    int oct = lane & 7;

    f32x4 xv[8];
    const float* xb = xp + n * DD + oct * 32;
#pragma unroll
    for (int t = 0; t < 8; t++) xv[t] = *(const f32x4*)(xb + t * 4);

    u32 myk = pkey[n * 32 + (lane & 31)] & 8191u;

    double bestv = 1e300;
    u32 besti = 0u;
#pragma unroll
    for (int g = 0; g < 4; g++) {
        int c = g * 8 + sub;
        u32 kg = (u32)__shfl((int)myk, c, 64);
        const float* cv = cbT + kg * DD + oct * 32;
        double s = 0.0;
#pragma unroll
        for (int t = 0; t < 8; t++) {
            f32x4 cvv = *(const f32x4*)(cv + t * 4);
#pragma unroll
            for (int q = 0; q < 4; q++) {
                double d = (double)xv[t][q] - (double)cvv[q];
                s += d * d;
            }
        }
        s += __shfl_xor(s, 1, 64);
        s += __shfl_xor(s, 2, 64);
        s += __shfl_xor(s, 4, 64);
        if (s < bestv || (s == bestv && kg < besti)) { bestv = s; besti = kg; }
    }
#pragma unroll
    for (int m = 8; m < 64; m <<= 1) {
        double ov = __shfl_xor(bestv, m, 64);
        u32 oi = (u32)__shfl_xor((int)besti, m, 64);
        if (ov < bestv || (ov == bestv && oi < besti)) { bestv = ov; besti = oi; }
    }
    if (lane == 0) {
        idxv[n] = besti;
        outIdx[n] = (float)besti;
        pmin[n] = (float)bestv;
    }
}

// ---------------------------------------------------------------------------
// K4: diff = sum(pmin)/(N*D), fp64. MUST run before k_gather (pmin lives in
// d_out chunk-0 scratch). One block of 1024 threads.
__global__ __launch_bounds__(1024) void k_final(const float* __restrict__ pmin,
                                                float* __restrict__ out) {
    __shared__ double sm[16];
    int tid = threadIdx.x, lane = tid & 63, wv = tid >> 6;
    double s = 0.0;
#pragma unroll
    for (int i = 0; i < 16; i++) s += (double)pmin[i * 1024 + tid];
#pragma unroll
    for (int m = 1; m < 64; m <<= 1) s += __shfl_xor(s, m, 64);
    if (lane == 0) sm[wv] = s;
    __syncthreads();
    if (tid == 0) {
        double t = 0.0;
#pragma unroll
        for (int i = 0; i < 16; i++) t += sm[i];
        out[0] = (float)(t * (1.0 / (double)OUT0));
    }
}

// ---------------------------------------------------------------------------
// K5: gather quantized (B,D,H,W) fp32 via LDS transpose tiles.
// Block handles 32 consecutive n (same b): read 32 winning rows as contiguous
// 1 KB bursts, transpose in LDS, write 128 B-contiguous output segments.
// Rewrites ALL of d_out chunk 0 (including every scratch byte).
__global__ __launch_bounds__(256) void k_gather(const float* __restrict__ cbT,
                                                const u32* __restrict__ idxv,
                                                float* __restrict__ out0) {
    __shared__ float tile[32 * 260];
    int tid = threadIdx.x;
    int n0 = blockIdx.x * 32;
    int b = n0 >> 10, hw0 = n0 & 1023;

    // Phase 1: 8 threads per row, 32 floats (8 f32x4) each.
    {
        int r = tid >> 3, seg = tid & 7;
        u32 k = idxv[n0 + r] & 8191u;
        const float* src = cbT + k * DD + seg * 32;
        float* dst = tile + r * 260 + seg * 32;
#pragma unroll
        for (int j = 0; j < 8; j++)
            *(f32x4*)(dst + j * 4) = *(const f32x4*)(src + j * 4);
    }
    __syncthreads();

    // Phase 2: thread = (dq = tid>>5: 8 d-groups) x (hw = tid&31).
    {
        int hw = tid & 31, dq = tid >> 5;
        const float* trow = tile + hw * 260;
        float* obase = out0 + ((size_t)b * DD) * HW + hw0 + hw;
#pragma unroll
        for (int dj = 0; dj < 32; dj++) {
            int d = dq * 32 + dj;
            obase[(size_t)d * HW] = trow[d];
        }
    }
}

// ---------------------------------------------------------------------------
extern "C" void kernel_launch(void* const* d_in, const int* in_sizes, int n_in,
                              void* d_out, int out_size, void* d_ws, size_t ws_size,
                              hipStream_t stream) {
    const float* x = nullptr; const float* Wm = nullptr;
    const float* bias = nullptr; const float* cb = nullptr;
    for (int i = 0; i < n_in; i++) {
        switch (in_sizes[i]) {
            case 4194304: x    = (const float*)d_in[i]; break;  // (16,256,32,32)
            case 65536:   Wm   = (const float*)d_in[i]; break;  // (256,256)
            case 256:     bias = (const float*)d_in[i]; break;  // (256,)
            case 2097152: cb   = (const float*)d_in[i]; break;  // (256,8192)
        }
    }

    // d_out is FP32: [quantized (4194304) | diff (1) | indices (16384)]
    float* out0    = (float*)d_out;
    float* outDiff = (float*)d_out + OUT0;
    float* outIdx  = (float*)d_out + OUT0 + 1;

    // Transient scratch inside d_out chunk 0 (16.7 MB fp32 region; every
    // byte rewritten by k_gather before the harness reads):
    char* o = (char*)d_out;
    u16*   cbTh = (u16*)o;                       // [0, 4 MB)
    u32*   pkey = (u32*)(o + 4194304);           // [4 MB, 6 MB)
    u16*   wh   = (u16*)(o + 6291456);           // 128 KB
    u16*   wm   = (u16*)(o + 6422528);           // 128 KB
    u16*   wl   = (u16*)(o + 6553600);           // 128 KB
    float* pmin = (float*)(o + 6684672);         // 64 KB (read by k_final BEFORE k_gather)

    // Workspace (25.26 MB, same footprint that passed):
    char* w = (char*)d_ws;
    float* cbT  = (float*)(w);                   // 8 MB  (K,D) fp32
    float* xp   = (float*)(w + 8388608);         // 16 MB (N,D) fp32
    float* cbnq = (float*)(w + 25165824);        // 32 KB
    u32*   idxv = (u32*)(w + 25198592);          // 64 KB

    k_canon<<<dim3(KK / 32, DD / 32), dim3(32, 8), 0, stream>>>(cb, cbT, cbTh);
    k_cbnorm<<<KK / 256, 256, 0, stream>>>(cb, cbnq);
    k_wsplit<<<(DD * CC) / 256, 256, 0, stream>>>(Wm, wh, wm, wl);
    k_proj<<<NN / 64, 256, 0, stream>>>(x, wh, wm, wl, bias, xp);
    k_dist<<<dim3(NN / 128, KSPLIT), 256, 0, stream>>>(xp, cbTh, cbnq, pkey);
    k_rescore<<<NN / 4, 256, 0, stream>>>(xp, cbT, pkey, idxv, outIdx, pmin);
    k_final<<<1, 1024, 0, stream>>>(pmin, outDiff);
    k_gather<<<NN / 32, 256, 0, stream>>>(cbT, idxv, out0);
}

// Round 7
// 295.327 us; speedup vs baseline: 1.8480x; 1.1706x over previous
//
#include <hip/hip_runtime.h>

typedef short bf16x8 __attribute__((ext_vector_type(8)));
typedef float f32x4 __attribute__((ext_vector_type(4)));
using u16 = unsigned short;
using u32 = unsigned int;

#define MFMA_BF16(A, B, C) __builtin_amdgcn_mfma_f32_16x16x32_bf16((A), (B), (C), 0, 0, 0)

#define CC 256
#define DD 256
#define KK 8192
#define NN 16384     // B*H*W
#define HW 1024      // H*W
#define OUT0 4194304 // B*D*H*W
#define KSPLIT 16
#define KROWS 32     // k-rows per LDS tile

static __device__ __forceinline__ float b2f(u16 u) {
    union { u32 i; float f; } v; v.i = ((u32)u) << 16; return v.f;
}
static __device__ __forceinline__ u16 f2b(float f) {  // RNE fp32 -> bf16
    union { float f; u32 i; } v; v.f = f;
    u32 x = v.i;
    u32 r = (x + 0x7fffu + ((x >> 16) & 1u)) >> 16;
    return (u16)r;
}
static __device__ __forceinline__ void split3(float v, u16& h, u16& m, u16& l) {
    h = f2b(v); float r1 = v - b2f(h);
    m = f2b(r1); float r2 = r1 - b2f(m);
    l = f2b(r2);
}

typedef __attribute__((address_space(1))) const u32 GlbU32;
typedef __attribute__((address_space(3))) u32 LdsU32;
static __device__ __forceinline__ void async_load16(const void* g, void* l) {
    // dst is wave-uniform base; HW writes lane i's 16B to base + i*16.
    __builtin_amdgcn_global_load_lds((GlbU32*)g, (LdsU32*)l, 16, 0, 0);
}

// ---------------------------------------------------------------------------
// K0a: transpose codebook (D,K) fp32 -> cbT (K,D) fp32 (ws) + cbTh (K,D) bf16.
__global__ __launch_bounds__(256) void k_canon(const float* __restrict__ cb,
                                               float* __restrict__ cbT,
                                               u16* __restrict__ cbTh) {
    __shared__ float tile[32][33];
    int k0 = blockIdx.x * 32, d0 = blockIdx.y * 32;
    int tx = threadIdx.x, ty = threadIdx.y;  // 32 x 8
#pragma unroll
    for (int i = 0; i < 4; i++) {
        int d = d0 + ty + i * 8;
        tile[ty + i * 8][tx] = cb[d * KK + k0 + tx];
    }
    __syncthreads();
#pragma unroll
    for (int i = 0; i < 4; i++) {
        int k = k0 + ty + i * 8;
        float v = tile[tx][ty + i * 8];
        cbT[k * DD + d0 + tx] = v;
        cbTh[k * DD + d0 + tx] = f2b(v);
    }
}

// ---------------------------------------------------------------------------
// K0b: cbnq[k] = 32*||c_k||^2 + 4096. Parallel: 256 blocks, 32 k x 8 d-strips.
__global__ __launch_bounds__(256) void k_cbnorm(const float* __restrict__ cb,
                                                float* __restrict__ cbnq) {
    __shared__ float sm[8][32];
    int tid = threadIdx.x;
    int kl = tid & 31, dg = tid >> 5;
    int k = blockIdx.x * 32 + kl;
    float s = 0.f;
#pragma unroll
    for (int j = 0; j < 32; j++) {
        float v = cb[(size_t)(dg * 32 + j) * KK + k];
        s += v * v;
    }
    sm[dg][kl] = s;
    __syncthreads();
    if (tid < 32) {
        float t = 0.f;
#pragma unroll
        for (int g = 0; g < 8; g++) t += sm[g][tid];
        cbnq[blockIdx.x * 32 + tid] = 32.f * t + 4096.f;
    }
}

// ---------------------------------------------------------------------------
// K0c: split conv_w (D,C) fp32 -> 3-way bf16 (hi/mid/lo), precomputed once.
__global__ __launch_bounds__(256) void k_wsplit(const float* __restrict__ Wm,
                                                u16* __restrict__ wh,
                                                u16* __restrict__ wm,
                                                u16* __restrict__ wl) {
    int t = blockIdx.x * 256 + threadIdx.x;
    u16 h, m, l; split3(Wm[t], h, m, l);
    wh[t] = h; wm[t] = m; wl[t] = l;
}

// ---------------------------------------------------------------------------
// K1: xp = x_r @ W^T + b via bf16x3 split MFMA (6 terms ~ fp32 accuracy).
// Also emits bf16 copy xpH for k_dist's A-frags.
__global__ __launch_bounds__(256) void k_proj(const float* __restrict__ x,
                                              const u16* __restrict__ wh,
                                              const u16* __restrict__ wm,
                                              const u16* __restrict__ wl,
                                              const float* __restrict__ bias,
                                              float* __restrict__ xp,
                                              u16* __restrict__ xpH) {
    int tid = threadIdx.x;
    int wave = tid >> 6, lane = tid & 63;
    int quad = lane >> 4, l15 = lane & 15;
    int n0 = (blockIdx.x * 4 + wave) * 16;
    int n_a = n0 + l15;
    const float* xb = x + (n_a >> 10) * (CC * HW) + (n_a & (HW - 1));

    f32x4 acc[16];
#pragma unroll
    for (int i = 0; i < 16; i++) acc[i] = (f32x4){0.f, 0.f, 0.f, 0.f};

#pragma unroll
    for (int cc = 0; cc < 8; cc++) {
        bf16x8 ah, am, al;
#pragma unroll
        for (int j = 0; j < 8; j++) {
            float v = xb[(cc * 32 + quad * 8 + j) * HW];
            u16 h, m, l; split3(v, h, m, l);
            ah[j] = (short)h; am[j] = (short)m; al[j] = (short)l;
        }
#pragma unroll
        for (int dt = 0; dt < 16; dt++) {
            int off = (dt * 16 + l15) * CC + cc * 32 + quad * 8;
            const bf16x8 bh = *(const bf16x8*)(wh + off);
            const bf16x8 bm = *(const bf16x8*)(wm + off);
            const bf16x8 bl = *(const bf16x8*)(wl + off);
            acc[dt] = MFMA_BF16(ah, bh, acc[dt]);
            acc[dt] = MFMA_BF16(am, bh, acc[dt]);
            acc[dt] = MFMA_BF16(ah, bm, acc[dt]);
            acc[dt] = MFMA_BF16(al, bh, acc[dt]);
            acc[dt] = MFMA_BF16(am, bm, acc[dt]);
            acc[dt] = MFMA_BF16(ah, bl, acc[dt]);
        }
    }

#pragma unroll
    for (int dt = 0; dt < 16; dt++) {
        int d = dt * 16 + l15;          // C-layout: col = lane&15
        float bv = bias[d];
#pragma unroll
        for (int r = 0; r < 4; r++) {
            int n = n0 + quad * 4 + r;  // C-layout: row = quad*4 + reg
            float v = acc[dt][r] + bv;
            xp[n * DD + d] = v;
            xpH[n * DD + d] = f2b(v);
        }
    }
}

// ---------------------------------------------------------------------------
// K2: approx distance GEMM + fused top-2 per (row-slot, lane) via packed keys.
// key = (u32)(cbnq[k] - 64*dot) << 13 | k.
// Double-buffered direct-to-LDS staging (global_load_lds, 16B) with XOR
// granule swizzle applied on the SOURCE address (LDS dst is lane-linear):
//   LDS[row][p] = cbTh[row][p ^ (row&7)]  (16B granules, 32 per 512B row)
// B-frag read: granule (dc*4+quad) ^ (klocal&7) -> uniform 8 words/bank.
__global__ __launch_bounds__(256) void k_dist(const u16* __restrict__ xpH,
                                              const u16* __restrict__ cbTh,
                                              const float* __restrict__ cbnq,
                                              u32* __restrict__ pkey) {
    __shared__ __align__(16) u16 tile[2][KROWS * 256];  // 2 x 16 KB
    int tid = threadIdx.x, wave = tid >> 6, lane = tid & 63;
    int quad = lane >> 4, l15 = lane & 15;
    int n0 = blockIdx.x * 128 + wave * 32;
    int ksbase = blockIdx.y * (KK / KSPLIT);   // 512 codes per split

    // A-frags (bf16) resident: 2 mt x 8 dc
    bf16x8 Ah[2][8];
#pragma unroll
    for (int mt = 0; mt < 2; mt++) {
        int n = n0 + mt * 16 + l15;
#pragma unroll
        for (int dc = 0; dc < 8; dc++)
            Ah[mt][dc] = *(const bf16x8*)(xpH + n * DD + dc * 32 + quad * 8);
    }

    u32 key1[2][4], key2[2][4];
#pragma unroll
    for (int mt = 0; mt < 2; mt++)
#pragma unroll
        for (int r = 0; r < 4; r++) { key1[mt][r] = 0xffffffffu; key2[mt][r] = 0xffffffffu; }

    // staging: 16 chunks of 1KB per tile; wave stages chunks wave*4..wave*4+3
#define STAGE(bufi, kglob_)                                                    \
    {                                                                          \
        int kg_ = (kglob_);                                                    \
        _Pragma("unroll")                                                      \
        for (int c = 0; c < 4; c++) {                                          \
            int chunk = wave * 4 + c;                                          \
            int row = chunk * 2 + (lane >> 5);                                 \
            int g = (lane & 31) ^ (row & 7);                                   \
            const u16* src = cbTh + (size_t)(kg_ + row) * DD + g * 8;          \
            async_load16(src, &tile[bufi][chunk * 512]);                       \
        }                                                                      \
    }

    STAGE(0, ksbase);
    __syncthreads();

    for (int kc = 0; kc < 16; kc++) {
        int buf = kc & 1;
        if (kc < 15) STAGE(buf ^ 1, ksbase + (kc + 1) * KROWS);

#pragma unroll
        for (int kt = 0; kt < 2; kt++) {
            int klocal = kt * 16 + l15;
            const u16* trow = &tile[buf][klocal * 256];
            bf16x8 Bf[8];
#pragma unroll
            for (int dc = 0; dc < 8; dc++) {
                int g = (dc * 4 + quad) ^ (l15 & 7);
                Bf[dc] = *(const bf16x8*)(trow + g * 8);
            }
            f32x4 a0 = (f32x4){0.f, 0.f, 0.f, 0.f};
            f32x4 a1 = (f32x4){0.f, 0.f, 0.f, 0.f};
#pragma unroll
            for (int dc = 0; dc < 8; dc++) {
                a0 = MFMA_BF16(Ah[0][dc], Bf[dc], a0);
                a1 = MFMA_BF16(Ah[1][dc], Bf[dc], a1);
            }
            u32 kg = (u32)(ksbase + kc * KROWS + klocal);
            float cq = cbnq[kg];
#pragma unroll
            for (int mt = 0; mt < 2; mt++) {
                f32x4 a = mt ? a1 : a0;
#pragma unroll
                for (int r = 0; r < 4; r++) {
                    u32 q = (u32)fmaf(a[r], -64.f, cq);
                    u32 key = (q << 13) | kg;
                    u32 t1 = min(key, key1[mt][r]);
                    u32 u1 = max(key, key1[mt][r]);
                    key1[mt][r] = t1;
                    key2[mt][r] = min(u1, key2[mt][r]);
                }
            }
        }
        __syncthreads();  // drains prefetch (issued ~700 cyc ago) + guards buffers
    }
#undef STAGE

    // merge top-2 across the 16 lanes (l15 groups) sharing the same C rows
#pragma unroll
    for (int mt = 0; mt < 2; mt++) {
#pragma unroll
        for (int r = 0; r < 4; r++) {
            u32 k1 = key1[mt][r], k2 = key2[mt][r];
#pragma unroll
            for (int m = 1; m < 16; m <<= 1) {
                u32 o1 = (u32)__shfl_xor((int)k1, m, 64);
                u32 o2 = (u32)__shfl_xor((int)k2, m, 64);
                u32 m1 = min(k1, o1);
                u32 M1 = max(k1, o1);
                k1 = m1;
                k2 = min(M1, min(k2, o2));
            }
            if (l15 == 0) {
                int n = n0 + mt * 16 + quad * 4 + r;
                int base = (n * KSPLIT + blockIdx.y) * 2;
                pkey[base] = k1; pkey[base + 1] = k2;
            }
        }
    }
}

// ---------------------------------------------------------------------------
// K3: exact fp64 rescore of 32 candidates per row. One wave per row.
__global__ __launch_bounds__(256) void k_rescore(const float* __restrict__ xp,
                                                 const float* __restrict__ cbT,
                                                 const u32* __restrict__ pkey,
                                                 u32* __restrict__ idxv,
                                                 float* __restrict__ outIdx,
                                                 float* __restrict__ pmin) {
    int tid = threadIdx.x, wave = tid >> 6, lane = tid & 63;
    int n = blockIdx.x * 4 + wave;
    int sub = lane >> 3;
    int oct = lane & 7;

    f32x4 xv[8];
    const float* xb = xp + n * DD + oct * 32;
#pragma unroll
    for (int t = 0; t < 8; t++) xv[t] = *(const f32x4*)(xb + t * 4);

    u32 myk = pkey[n * 32 + (lane & 31)] & 8191u;

    double bestv = 1e300;
    u32 besti = 0u;
#pragma unroll
    for (int g = 0; g < 4; g++) {
        int c = g * 8 + sub;
        u32 kg = (u32)__shfl((int)myk, c, 64);
        const float* cv = cbT + kg * DD + oct * 32;
        double s = 0.0;
#pragma unroll
        for (int t = 0; t < 8; t++) {
            f32x4 cvv = *(const f32x4*)(cv + t * 4);
#pragma unroll
            for (int q = 0; q < 4; q++) {
                double d = (double)xv[t][q] - (double)cvv[q];
                s += d * d;
            }
        }
        s += __shfl_xor(s, 1, 64);
        s += __shfl_xor(s, 2, 64);
        s += __shfl_xor(s, 4, 64);
        if (s < bestv || (s == bestv && kg < besti)) { bestv = s; besti = kg; }
    }
#pragma unroll
    for (int m = 8; m < 64; m <<= 1) {
        double ov = __shfl_xor(bestv, m, 64);
        u32 oi = (u32)__shfl_xor((int)besti, m, 64);
        if (ov < bestv || (ov == bestv && oi < besti)) { bestv = ov; besti = oi; }
    }
    if (lane == 0) {
        idxv[n] = besti;
        outIdx[n] = (float)besti;
        pmin[n] = (float)bestv;
    }
}

// ---------------------------------------------------------------------------
// K4: diff = sum(pmin)/(N*D), fp64. MUST run before k_gather (pmin is d_out
// scratch). One block of 1024 threads.
__global__ __launch_bounds__(1024) void k_final(const float* __restrict__ pmin,
                                                float* __restrict__ out) {
    __shared__ double sm[16];
    int tid = threadIdx.x, lane = tid & 63, wv = tid >> 6;
    double s = 0.0;
#pragma unroll
    for (int i = 0; i < 16; i++) s += (double)pmin[i * 1024 + tid];
#pragma unroll
    for (int m = 1; m < 64; m <<= 1) s += __shfl_xor(s, m, 64);
    if (lane == 0) sm[wv] = s;
    __syncthreads();
    if (tid == 0) {
        double t = 0.0;
#pragma unroll
        for (int i = 0; i < 16; i++) t += sm[i];
        out[0] = (float)(t * (1.0 / (double)OUT0));
    }
}

// ---------------------------------------------------------------------------
// K5: gather quantized (B,D,H,W) fp32 via LDS transpose tiles. Rewrites ALL
// of d_out chunk 0 (every scratch byte).
__global__ __launch_bounds__(256) void k_gather(const float* __restrict__ cbT,
                                                const u32* __restrict__ idxv,
                                                float* __restrict__ out0) {
    __shared__ float tile[32 * 260];
    int tid = threadIdx.x;
    int n0 = blockIdx.x * 32;
    int b = n0 >> 10, hw0 = n0 & 1023;

    {
        int r = tid >> 3, seg = tid & 7;
        u32 k = idxv[n0 + r] & 8191u;
        const float* src = cbT + k * DD + seg * 32;
        float* dst = tile + r * 260 + seg * 32;
#pragma unroll
        for (int j = 0; j < 8; j++)
            *(f32x4*)(dst + j * 4) = *(const f32x4*)(src + j * 4);
    }
    __syncthreads();
    {
        int hw = tid & 31, dq = tid >> 5;
        const float* trow = tile + hw * 260;
        float* obase = out0 + ((size_t)b * DD) * HW + hw0 + hw;
#pragma unroll
        for (int dj = 0; dj < 32; dj++) {
            int d = dq * 32 + dj;
            obase[(size_t)d * HW] = trow[d];
        }
    }
}

// ---------------------------------------------------------------------------
extern "C" void kernel_launch(void* const* d_in, const int* in_sizes, int n_in,
                              void* d_out, int out_size, void* d_ws, size_t ws_size,
                              hipStream_t stream) {
    const float* x = nullptr; const float* Wm = nullptr;
    const float* bias = nullptr; const float* cb = nullptr;
    for (int i = 0; i < n_in; i++) {
        switch (in_sizes[i]) {
            case 4194304: x    = (const float*)d_in[i]; break;  // (16,256,32,32)
            case 65536:   Wm   = (const float*)d_in[i]; break;  // (256,256)
            case 256:     bias = (const float*)d_in[i]; break;  // (256,)
            case 2097152: cb   = (const float*)d_in[i]; break;  // (256,8192)
        }
    }

    // d_out is FP32: [quantized (4194304) | diff (1) | indices (16384)]
    float* out0    = (float*)d_out;
    float* outDiff = (float*)d_out + OUT0;
    float* outIdx  = (float*)d_out + OUT0 + 1;

    // Transient scratch inside d_out chunk 0 (16.78 MB; every byte rewritten
    // by k_gather before the harness reads):
    char* o = (char*)d_out;
    u16*   cbTh = (u16*)o;                       // [0, 4 MB)
    u32*   pkey = (u32*)(o + 4194304);           // [4 MB, 6 MB)
    u16*   wh   = (u16*)(o + 6291456);           // 128 KB
    u16*   wm   = (u16*)(o + 6422528);           // 128 KB
    u16*   wl   = (u16*)(o + 6553600);           // 128 KB
    float* pmin = (float*)(o + 6684672);         // 64 KB (read by k_final BEFORE k_gather)
    u16*   xpH  = (u16*)(o + 6750208);           // 8 MB  (N,D) bf16  -> ends 14.75 MB

    // Workspace (25.26 MB, same footprint that passed):
    char* w = (char*)d_ws;
    float* cbT  = (float*)(w);                   // 8 MB  (K,D) fp32
    float* xp   = (float*)(w + 8388608);         // 16 MB (N,D) fp32
    float* cbnq = (float*)(w + 25165824);        // 32 KB
    u32*   idxv = (u32*)(w + 25198592);          // 64 KB

    k_canon<<<dim3(KK / 32, DD / 32), dim3(32, 8), 0, stream>>>(cb, cbT, cbTh);
    k_cbnorm<<<KK / 32, 256, 0, stream>>>(cb, cbnq);
    k_wsplit<<<(DD * CC) / 256, 256, 0, stream>>>(Wm, wh, wm, wl);
    k_proj<<<NN / 64, 256, 0, stream>>>(x, wh, wm, wl, bias, xp, xpH);
    k_dist<<<dim3(NN / 128, KSPLIT), 256, 0, stream>>>(xpH, cbTh, cbnq, pkey);
    k_rescore<<<NN / 4, 256, 0, stream>>>(xp, cbT, pkey, idxv, outIdx, pmin);
    k_final<<<1, 1024, 0, stream>>>(pmin, outDiff);
    k_gather<<<NN / 32, 256, 0, stream>>>(cbT, idxv, out0);
}

// Round 8
// 292.710 us; speedup vs baseline: 1.8646x; 1.0089x over previous
//
#include <hip/hip_runtime.h>

typedef short bf16x8 __attribute__((ext_vector_type(8)));
typedef float f32x4 __attribute__((ext_vector_type(4)));
using u16 = unsigned short;
using u32 = unsigned int;

#define MFMA_BF16(A, B, C) __builtin_amdgcn_mfma_f32_16x16x32_bf16((A), (B), (C), 0, 0, 0)

#define CC 256
#define DD 256
#define KK 8192
#define NN 16384     // B*H*W
#define HW 1024      // H*W
#define OUT0 4194304 // B*D*H*W
#define KSPLIT 16
#define KROWS 32     // k-rows per LDS tile

static __device__ __forceinline__ float b2f(u16 u) {
    union { u32 i; float f; } v; v.i = ((u32)u) << 16; return v.f;
}
static __device__ __forceinline__ u16 f2b(float f) {  // RNE fp32 -> bf16
    union { float f; u32 i; } v; v.f = f;
    u32 x = v.i;
    u32 r = (x + 0x7fffu + ((x >> 16) & 1u)) >> 16;
    return (u16)r;
}
static __device__ __forceinline__ u32 f2u(float f) {
    union { float f; u32 u; } v; v.f = f; return v.u;
}
static __device__ __forceinline__ void split3(float v, u16& h, u16& m, u16& l) {
    h = f2b(v); float r1 = v - b2f(h);
    m = f2b(r1); float r2 = r1 - b2f(m);
    l = f2b(r2);
}

typedef __attribute__((address_space(1))) const u32 GlbU32;
typedef __attribute__((address_space(3))) u32 LdsU32;
static __device__ __forceinline__ void async_load16(const void* g, void* l) {
    __builtin_amdgcn_global_load_lds((GlbU32*)g, (LdsU32*)l, 16, 0, 0);
}

// ---------------------------------------------------------------------------
// K0 (fused prep): blocks [0,2048): transpose cb -> cbT fp32 + cbTh bf16;
// blocks [2048,2304): negC0[k] = -0.5*(||c_k||^2 + 1024);
// blocks [2304,2560): 3-way bf16 split of conv_w.
__global__ __launch_bounds__(256) void k_prep(const float* __restrict__ cb,
                                              const float* __restrict__ Wm,
                                              float* __restrict__ cbT,
                                              u16* __restrict__ cbTh,
                                              float* __restrict__ negC0,
                                              u16* __restrict__ wh,
                                              u16* __restrict__ wm,
                                              u16* __restrict__ wl) {
    int bx = blockIdx.x, tid = threadIdx.x;
    if (bx < 2048) {
        __shared__ float tile[32][33];
        int k0 = (bx & 255) * 32, d0 = (bx >> 8) * 32;
        int tx = tid & 31, ty = tid >> 5;  // 32 x 8
#pragma unroll
        for (int i = 0; i < 4; i++) {
            int d = d0 + ty + i * 8;
            tile[ty + i * 8][tx] = cb[d * KK + k0 + tx];
        }
        __syncthreads();
#pragma unroll
        for (int i = 0; i < 4; i++) {
            int k = k0 + ty + i * 8;
            float v = tile[tx][ty + i * 8];
            cbT[k * DD + d0 + tx] = v;
            cbTh[k * DD + d0 + tx] = f2b(v);
        }
    } else if (bx < 2304) {
        __shared__ float sm[8][32];
        int kl = tid & 31, dg = tid >> 5;
        int k = (bx - 2048) * 32 + kl;
        float s = 0.f;
#pragma unroll
        for (int j = 0; j < 32; j++) {
            float v = cb[(size_t)(dg * 32 + j) * KK + k];
            s += v * v;
        }
        sm[dg][kl] = s;
        __syncthreads();
        if (tid < 32) {
            float t = 0.f;
#pragma unroll
            for (int g = 0; g < 8; g++) t += sm[g][tid];
            negC0[(bx - 2048) * 32 + tid] = -0.5f * (t + 1024.f);
        }
    } else {
        int t = (bx - 2304) * 256 + tid;
        u16 h, m, l; split3(Wm[t], h, m, l);
        wh[t] = h; wm[t] = m; wl[t] = l;
    }
}

// ---------------------------------------------------------------------------
// K1: xp = x_r @ W^T + b via bf16x3 split MFMA (6 terms ~ fp32 accuracy).
// Also emits bf16 copy xpH for k_dist's A-frags.
__global__ __launch_bounds__(256) void k_proj(const float* __restrict__ x,
                                              const u16* __restrict__ wh,
                                              const u16* __restrict__ wm,
                                              const u16* __restrict__ wl,
                                              const float* __restrict__ bias,
                                              float* __restrict__ xp,
                                              u16* __restrict__ xpH) {
    int tid = threadIdx.x;
    int wave = tid >> 6, lane = tid & 63;
    int quad = lane >> 4, l15 = lane & 15;
    int n0 = (blockIdx.x * 4 + wave) * 16;
    int n_a = n0 + l15;
    const float* xb = x + (n_a >> 10) * (CC * HW) + (n_a & (HW - 1));

    f32x4 acc[16];
#pragma unroll
    for (int i = 0; i < 16; i++) acc[i] = (f32x4){0.f, 0.f, 0.f, 0.f};

#pragma unroll
    for (int cc = 0; cc < 8; cc++) {
        bf16x8 ah, am, al;
#pragma unroll
        for (int j = 0; j < 8; j++) {
            float v = xb[(cc * 32 + quad * 8 + j) * HW];
            u16 h, m, l; split3(v, h, m, l);
            ah[j] = (short)h; am[j] = (short)m; al[j] = (short)l;
        }
#pragma unroll
        for (int dt = 0; dt < 16; dt++) {
            int off = (dt * 16 + l15) * CC + cc * 32 + quad * 8;
            const bf16x8 bh = *(const bf16x8*)(wh + off);
            const bf16x8 bm = *(const bf16x8*)(wm + off);
            const bf16x8 bl = *(const bf16x8*)(wl + off);
            acc[dt] = MFMA_BF16(ah, bh, acc[dt]);
            acc[dt] = MFMA_BF16(am, bh, acc[dt]);
            acc[dt] = MFMA_BF16(ah, bm, acc[dt]);
            acc[dt] = MFMA_BF16(al, bh, acc[dt]);
            acc[dt] = MFMA_BF16(am, bm, acc[dt]);
            acc[dt] = MFMA_BF16(ah, bl, acc[dt]);
        }
    }

#pragma unroll
    for (int dt = 0; dt < 16; dt++) {
        int d = dt * 16 + l15;          // C-layout: col = lane&15
        float bv = bias[d];
#pragma unroll
        for (int r = 0; r < 4; r++) {
            int n = n0 + quad * 4 + r;  // C-layout: row = quad*4 + reg
            float v = acc[dt][r] + bv;
            xp[n * DD + d] = v;
            xpH[n * DD + d] = f2b(v);
        }
    }
}

// ---------------------------------------------------------------------------
// K2: approx distance GEMM + fused argmin-candidate selection.
// MFMA accumulator is initialized to negC0[k] = -(||c||^2+1024)/2, so the
// MFMA output a = x.c - (||c||^2+1024)/2 is strictly negative and u32-bit
// comparison on it gives exact score order (min dist = min u32 bits).
// key = (bits(a) & ~0x1FF) | (iter<<4) | l15  (self-describing; kg = ksbase
// + (key & 511)). Per score: v_and_or + v_min_u32 = 2 VALU.
// Per-lane top-1 -> cross-lane top-2 per split (equivalent argmin protection
// to split-wide top-2). Double-buffered global_load_lds staging (round 7).
__global__ __launch_bounds__(256) void k_dist(const u16* __restrict__ xpH,
                                              const u16* __restrict__ cbTh,
                                              const float* __restrict__ negC0,
                                              u32* __restrict__ pkey) {
    __shared__ __align__(16) u16 tile[2][KROWS * 256];  // 2 x 16 KB
    int tid = threadIdx.x, wave = tid >> 6, lane = tid & 63;
    int quad = lane >> 4, l15 = lane & 15;
    int n0 = blockIdx.x * 128 + wave * 32;
    int ksbase = blockIdx.y * (KK / KSPLIT);   // 512 codes per split

    // A-frags (bf16) resident: 2 mt x 8 dc
    bf16x8 Ah[2][8];
#pragma unroll
    for (int mt = 0; mt < 2; mt++) {
        int n = n0 + mt * 16 + l15;
#pragma unroll
        for (int dc = 0; dc < 8; dc++)
            Ah[mt][dc] = *(const bf16x8*)(xpH + n * DD + dc * 32 + quad * 8);
    }

    // Preload accumulator inits for this lane's 32 (kc,kt) k-columns.
    float nc[32];
#pragma unroll
    for (int i = 0; i < 32; i++) nc[i] = negC0[ksbase + i * 16 + l15];

    u32 key1[2][4];
#pragma unroll
    for (int mt = 0; mt < 2; mt++)
#pragma unroll
        for (int r = 0; r < 4; r++) key1[mt][r] = 0xffffffffu;

#define STAGE(bufi, kglob_)                                                    \
    {                                                                          \
        int kg_ = (kglob_);                                                    \
        _Pragma("unroll")                                                      \
        for (int c = 0; c < 4; c++) {                                          \
            int chunk = wave * 4 + c;                                          \
            int row = chunk * 2 + (lane >> 5);                                 \
            int g = (lane & 31) ^ (row & 7);                                   \
            const u16* src = cbTh + (size_t)(kg_ + row) * DD + g * 8;          \
            async_load16(src, &tile[bufi][chunk * 512]);                       \
        }                                                                      \
    }

    STAGE(0, ksbase);
    __syncthreads();

    for (int kc = 0; kc < 16; kc++) {
        int buf = kc & 1;
        if (kc < 15) STAGE(buf ^ 1, ksbase + (kc + 1) * KROWS);

        u32 orv0 = ((u32)kc << 5) | (u32)l15;
#pragma unroll
        for (int kt = 0; kt < 2; kt++) {
            int klocal = kt * 16 + l15;
            const u16* trow = &tile[buf][klocal * 256];
            bf16x8 Bf[8];
#pragma unroll
            for (int dc = 0; dc < 8; dc++) {
                int g = (dc * 4 + quad) ^ (l15 & 7);
                Bf[dc] = *(const bf16x8*)(trow + g * 8);
            }
            float init = nc[kc * 2 + kt];
            f32x4 a0 = (f32x4){init, init, init, init};
            f32x4 a1 = a0;
#pragma unroll
            for (int dc = 0; dc < 8; dc++) {
                a0 = MFMA_BF16(Ah[0][dc], Bf[dc], a0);
                a1 = MFMA_BF16(Ah[1][dc], Bf[dc], a1);
            }
            u32 orv = orv0 + ((u32)kt << 4);
#pragma unroll
            for (int mt = 0; mt < 2; mt++) {
                f32x4 a = mt ? a1 : a0;
#pragma unroll
                for (int r = 0; r < 4; r++) {
                    u32 kb = (f2u(a[r]) & 0xFFFFFE00u) | orv;
                    key1[mt][r] = min(key1[mt][r], kb);
                }
            }
        }
        __syncthreads();  // drains prefetch + guards buffers
    }
#undef STAGE

    // top-2 of the 16 per-lane minima within each quad group (same C rows)
#pragma unroll
    for (int mt = 0; mt < 2; mt++) {
#pragma unroll
        for (int r = 0; r < 4; r++) {
            u32 k1 = key1[mt][r], k2 = 0xffffffffu;
#pragma unroll
            for (int m = 1; m < 16; m <<= 1) {
                u32 o1 = (u32)__shfl_xor((int)k1, m, 64);
                u32 o2 = (u32)__shfl_xor((int)k2, m, 64);
                u32 mx = max(k1, o1);
                k1 = min(k1, o1);
                k2 = min(min(k2, o2), mx);
            }
            if (l15 == 0) {
                int n = n0 + mt * 16 + quad * 4 + r;
                int base = (n * KSPLIT + blockIdx.y) * 2;
                pkey[base]     = (u32)ksbase + (k1 & 511u);
                pkey[base + 1] = (u32)ksbase + (k2 & 511u);
            }
        }
    }
}

// ---------------------------------------------------------------------------
// K3: exact fp64 rescore of 32 candidates per row. One wave per row.
__global__ __launch_bounds__(256) void k_rescore(const float* __restrict__ xp,
                                                 const float* __restrict__ cbT,
                                                 const u32* __restrict__ pkey,
                                                 u32* __restrict__ idxv,
                                                 float* __restrict__ outIdx,
                                                 float* __restrict__ pmin) {
    int tid = threadIdx.x, wave = tid >> 6, lane = tid & 63;
    int n = blockIdx.x * 4 + wave;
    int sub = lane >> 3;
    int oct = lane & 7;

    f32x4 xv[8];
    const float* xb = xp + n * DD + oct * 32;
#pragma unroll
    for (int t = 0; t < 8; t++) xv[t] = *(const f32x4*)(xb + t * 4);

    u32 myk = pkey[n * 32 + (lane & 31)] & 8191u;

    double bestv = 1e300;
    u32 besti = 0u;
#pragma unroll
    for (int g = 0; g < 4; g++) {
        int c = g * 8 + sub;
        u32 kg = (u32)__shfl((int)myk, c, 64);
        const float* cv = cbT + kg * DD + oct * 32;
        double s = 0.0;
#pragma unroll
        for (int t = 0; t < 8; t++) {
            f32x4 cvv = *(const f32x4*)(cv + t * 4);
#pragma unroll
            for (int q = 0; q < 4; q++) {
                double d = (double)xv[t][q] - (double)cvv[q];
                s += d * d;
            }
        }
        s += __shfl_xor(s, 1, 64);
        s += __shfl_xor(s, 2, 64);
        s += __shfl_xor(s, 4, 64);
        if (s < bestv || (s == bestv && kg < besti)) { bestv = s; besti = kg; }
    }
#pragma unroll
    for (int m = 8; m < 64; m <<= 1) {
        double ov = __shfl_xor(bestv, m, 64);
        u32 oi = (u32)__shfl_xor((int)besti, m, 64);
        if (ov < bestv || (ov == bestv && oi < besti)) { bestv = ov; besti = oi; }
    }
    if (lane == 0) {
        idxv[n] = besti;
        outIdx[n] = (float)besti;
        pmin[n] = (float)bestv;
    }
}

// ---------------------------------------------------------------------------
// K4: diff = sum(pmin)/(N*D), fp64 (pmin in ws, no ordering constraint).
__global__ __launch_bounds__(1024) void k_final(const float* __restrict__ pmin,
                                                float* __restrict__ out) {
    __shared__ double sm[16];
    int tid = threadIdx.x, lane = tid & 63, wv = tid >> 6;
    double s = 0.0;
#pragma unroll
    for (int i = 0; i < 16; i++) s += (double)pmin[i * 1024 + tid];
#pragma unroll
    for (int m = 1; m < 64; m <<= 1) s += __shfl_xor(s, m, 64);
    if (lane == 0) sm[wv] = s;
    __syncthreads();
    if (tid == 0) {
        double t = 0.0;
#pragma unroll
        for (int i = 0; i < 16; i++) t += sm[i];
        out[0] = (float)(t * (1.0 / (double)OUT0));
    }
}

// ---------------------------------------------------------------------------
// K5: gather quantized (B,D,H,W) fp32 via LDS transpose tiles. Rewrites ALL
// of d_out chunk 0 (every scratch byte).
__global__ __launch_bounds__(256) void k_gather(const float* __restrict__ cbT,
                                                const u32* __restrict__ idxv,
                                                float* __restrict__ out0) {
    __shared__ float tile[32 * 260];
    int tid = threadIdx.x;
    int n0 = blockIdx.x * 32;
    int b = n0 >> 10, hw0 = n0 & 1023;

    {
        int r = tid >> 3, seg = tid & 7;
        u32 k = idxv[n0 + r] & 8191u;
        const float* src = cbT + k * DD + seg * 32;
        float* dst = tile + r * 260 + seg * 32;
#pragma unroll
        for (int j = 0; j < 8; j++)
            *(f32x4*)(dst + j * 4) = *(const f32x4*)(src + j * 4);
    }
    __syncthreads();
    {
        int hw = tid & 31, dq = tid >> 5;
        const float* trow = tile + hw * 260;
        float* obase = out0 + ((size_t)b * DD) * HW + hw0 + hw;
#pragma unroll
        for (int dj = 0; dj < 32; dj++) {
            int d = dq * 32 + dj;
            obase[(size_t)d * HW] = trow[d];
        }
    }
}

// ---------------------------------------------------------------------------
extern "C" void kernel_launch(void* const* d_in, const int* in_sizes, int n_in,
                              void* d_out, int out_size, void* d_ws, size_t ws_size,
                              hipStream_t stream) {
    const float* x = nullptr; const float* Wm = nullptr;
    const float* bias = nullptr; const float* cb = nullptr;
    for (int i = 0; i < n_in; i++) {
        switch (in_sizes[i]) {
            case 4194304: x    = (const float*)d_in[i]; break;  // (16,256,32,32)
            case 65536:   Wm   = (const float*)d_in[i]; break;  // (256,256)
            case 256:     bias = (const float*)d_in[i]; break;  // (256,)
            case 2097152: cb   = (const float*)d_in[i]; break;  // (256,8192)
        }
    }

    // d_out is FP32: [quantized (4194304) | diff (1) | indices (16384)]
    float* out0    = (float*)d_out;
    float* outDiff = (float*)d_out + OUT0;
    float* outIdx  = (float*)d_out + OUT0 + 1;

    // Transient scratch inside d_out chunk 0 (16.78 MB; every byte rewritten
    // by k_gather before the harness reads):
    char* o = (char*)d_out;
    u16*   cbTh = (u16*)o;                       // [0, 4 MB)
    u32*   pkey = (u32*)(o + 4194304);           // [4 MB, 6 MB)
    u16*   wh   = (u16*)(o + 6291456);           // 128 KB
    u16*   wm   = (u16*)(o + 6422528);           // 128 KB
    u16*   wl   = (u16*)(o + 6553600);           // 128 KB
    u16*   xpH  = (u16*)(o + 6750208);           // 8 MB  (N,D) bf16 -> ends 14.75 MB

    // Workspace (~25.33 MB, footprint that passed in rounds 4-7):
    char* w = (char*)d_ws;
    float* cbT   = (float*)(w);                  // 8 MB  (K,D) fp32
    float* xp    = (float*)(w + 8388608);        // 16 MB (N,D) fp32
    float* negC0 = (float*)(w + 25165824);       // 32 KB
    u32*   idxv  = (u32*)(w + 25198592);         // 64 KB
    float* pmin  = (float*)(w + 25264128);       // 64 KB

    k_prep<<<2560, 256, 0, stream>>>(cb, Wm, cbT, cbTh, negC0, wh, wm, wl);
    k_proj<<<NN / 64, 256, 0, stream>>>(x, wh, wm, wl, bias, xp, xpH);
    k_dist<<<dim3(NN / 128, KSPLIT), 256, 0, stream>>>(xpH, cbTh, negC0, pkey);
    k_rescore<<<NN / 4, 256, 0, stream>>>(xp, cbT, pkey, idxv, outIdx, pmin);
    k_final<<<1, 1024, 0, stream>>>(pmin, outDiff);
    k_gather<<<NN / 32, 256, 0, stream>>>(cbT, idxv, out0);
}

// Round 9
// 291.569 us; speedup vs baseline: 1.8719x; 1.0039x over previous
//
#include <hip/hip_runtime.h>

typedef short bf16x8 __attribute__((ext_vector_type(8)));
typedef float f32x4 __attribute__((ext_vector_type(4)));
typedef float f32x16 __attribute__((ext_vector_type(16)));
using u16 = unsigned short;
using u32 = unsigned int;

#define MFMA_BF16(A, B, C) __builtin_amdgcn_mfma_f32_16x16x32_bf16((A), (B), (C), 0, 0, 0)
#define MFMA32_BF16(A, B, C) __builtin_amdgcn_mfma_f32_32x32x16_bf16((A), (B), (C), 0, 0, 0)

#define CC 256
#define DD 256
#define KK 8192
#define NN 16384     // B*H*W
#define HW 1024      // H*W
#define OUT0 4194304 // B*D*H*W
#define KSPLIT 16
#define KROWS 32     // k-rows (codes) per LDS tile

static __device__ __forceinline__ float b2f(u16 u) {
    union { u32 i; float f; } v; v.i = ((u32)u) << 16; return v.f;
}
static __device__ __forceinline__ u16 f2b(float f) {  // RNE fp32 -> bf16
    union { float f; u32 i; } v; v.f = f;
    u32 x = v.i;
    u32 r = (x + 0x7fffu + ((x >> 16) & 1u)) >> 16;
    return (u16)r;
}
static __device__ __forceinline__ u32 f2u(float f) {
    union { float f; u32 u; } v; v.f = f; return v.u;
}
static __device__ __forceinline__ void split3(float v, u16& h, u16& m, u16& l) {
    h = f2b(v); float r1 = v - b2f(h);
    m = f2b(r1); float r2 = r1 - b2f(m);
    l = f2b(r2);
}

typedef __attribute__((address_space(1))) const u32 GlbU32;
typedef __attribute__((address_space(3))) u32 LdsU32;
static __device__ __forceinline__ void async_load16(const void* g, void* l) {
    __builtin_amdgcn_global_load_lds((GlbU32*)g, (LdsU32*)l, 16, 0, 0);
}

// ---------------------------------------------------------------------------
// K0 (fused prep): blocks [0,2048): transpose cb -> cbT fp32 + cbTh bf16;
// blocks [2048,2304): negC0[k] = -0.5*(||c_k||^2 + 1024);
// blocks [2304,2560): 3-way bf16 split of conv_w.
__global__ __launch_bounds__(256) void k_prep(const float* __restrict__ cb,
                                              const float* __restrict__ Wm,
                                              float* __restrict__ cbT,
                                              u16* __restrict__ cbTh,
                                              float* __restrict__ negC0,
                                              u16* __restrict__ wh,
                                              u16* __restrict__ wm,
                                              u16* __restrict__ wl) {
    int bx = blockIdx.x, tid = threadIdx.x;
    if (bx < 2048) {
        __shared__ float tile[32][33];
        int k0 = (bx & 255) * 32, d0 = (bx >> 8) * 32;
        int tx = tid & 31, ty = tid >> 5;  // 32 x 8
#pragma unroll
        for (int i = 0; i < 4; i++) {
            int d = d0 + ty + i * 8;
            tile[ty + i * 8][tx] = cb[d * KK + k0 + tx];
        }
        __syncthreads();
#pragma unroll
        for (int i = 0; i < 4; i++) {
            int k = k0 + ty + i * 8;
            float v = tile[tx][ty + i * 8];
            cbT[k * DD + d0 + tx] = v;
            cbTh[k * DD + d0 + tx] = f2b(v);
        }
    } else if (bx < 2304) {
        __shared__ float sm[8][32];
        int kl = tid & 31, dg = tid >> 5;
        int k = (bx - 2048) * 32 + kl;
        float s = 0.f;
#pragma unroll
        for (int j = 0; j < 32; j++) {
            float v = cb[(size_t)(dg * 32 + j) * KK + k];
            s += v * v;
        }
        sm[dg][kl] = s;
        __syncthreads();
        if (tid < 32) {
            float t = 0.f;
#pragma unroll
            for (int g = 0; g < 8; g++) t += sm[g][tid];
            negC0[(bx - 2048) * 32 + tid] = -0.5f * (t + 1024.f);
        }
    } else {
        int t = (bx - 2304) * 256 + tid;
        u16 h, m, l; split3(Wm[t], h, m, l);
        wh[t] = h; wm[t] = m; wl[t] = l;
    }
}

// ---------------------------------------------------------------------------
// K1: xp = x_r @ W^T + b via bf16x3 split MFMA (6 terms ~ fp32 accuracy).
// Also emits bf16 copy xpH for k_dist's A-frags.
__global__ __launch_bounds__(256) void k_proj(const float* __restrict__ x,
                                              const u16* __restrict__ wh,
                                              const u16* __restrict__ wm,
                                              const u16* __restrict__ wl,
                                              const float* __restrict__ bias,
                                              float* __restrict__ xp,
                                              u16* __restrict__ xpH) {
    int tid = threadIdx.x;
    int wave = tid >> 6, lane = tid & 63;
    int quad = lane >> 4, l15 = lane & 15;
    int n0 = (blockIdx.x * 4 + wave) * 16;
    int n_a = n0 + l15;
    const float* xb = x + (n_a >> 10) * (CC * HW) + (n_a & (HW - 1));

    f32x4 acc[16];
#pragma unroll
    for (int i = 0; i < 16; i++) acc[i] = (f32x4){0.f, 0.f, 0.f, 0.f};

#pragma unroll
    for (int cc = 0; cc < 8; cc++) {
        bf16x8 ah, am, al;
#pragma unroll
        for (int j = 0; j < 8; j++) {
            float v = xb[(cc * 32 + quad * 8 + j) * HW];
            u16 h, m, l; split3(v, h, m, l);
            ah[j] = (short)h; am[j] = (short)m; al[j] = (short)l;
        }
#pragma unroll
        for (int dt = 0; dt < 16; dt++) {
            int off = (dt * 16 + l15) * CC + cc * 32 + quad * 8;
            const bf16x8 bh = *(const bf16x8*)(wh + off);
            const bf16x8 bm = *(const bf16x8*)(wm + off);
            const bf16x8 bl = *(const bf16x8*)(wl + off);
            acc[dt] = MFMA_BF16(ah, bh, acc[dt]);
            acc[dt] = MFMA_BF16(am, bh, acc[dt]);
            acc[dt] = MFMA_BF16(ah, bm, acc[dt]);
            acc[dt] = MFMA_BF16(al, bh, acc[dt]);
            acc[dt] = MFMA_BF16(am, bm, acc[dt]);
            acc[dt] = MFMA_BF16(ah, bl, acc[dt]);
        }
    }

#pragma unroll
    for (int dt = 0; dt < 16; dt++) {
        int d = dt * 16 + l15;          // C-layout: col = lane&15
        float bv = bias[d];
#pragma unroll
        for (int r = 0; r < 4; r++) {
            int n = n0 + quad * 4 + r;  // C-layout: row = quad*4 + reg
            float v = acc[dt][r] + bv;
            xp[n * DD + d] = v;
            xpH[n * DD + d] = f2b(v);
        }
    }
}

// ---------------------------------------------------------------------------
// K2: approx distance GEMM (32x32x16 MFMA) + fused argmin-candidate select.
// Acc init = negC0[col] = -(||c||^2+1024)/2 => MFMA output is the (strictly
// negative) score; u32-bit min == dist min. key = (bits & ~0x1FF) | (kc<<5|col).
// 64 rows/wave (2 m-tiles) share each B-frag: 2x MAC per LDS byte vs 16x16.
// A/B layout: idx = lane&31, k = 8*(lane>>5)+j.  C/D (verified m74/m101):
// col = lane&31, row = (reg&3) + 8*(reg>>2) + 4*(lane>>5).
__global__ __launch_bounds__(256, 2) void k_dist(const u16* __restrict__ xpH,
                                                 const u16* __restrict__ cbTh,
                                                 const float* __restrict__ negC0,
                                                 u32* __restrict__ pkey) {
    __shared__ __align__(16) u16 tile[2][KROWS * 256];  // 2 x 16 KB
    int tid = threadIdx.x, wave = tid >> 6, lane = tid & 63;
    int col = lane & 31, half = lane >> 5;
    int n0 = blockIdx.x * 256 + wave * 64;
    int ksbase = blockIdx.y * (KK / KSPLIT);   // 512 codes per split

    // A-frags resident: 2 mt x 16 ks (row = col, dims ks*16 + half*8 + j)
    bf16x8 Ah[2][16];
#pragma unroll
    for (int mt = 0; mt < 2; mt++) {
        const u16* ab = xpH + (size_t)(n0 + mt * 32 + col) * DD + half * 8;
#pragma unroll
        for (int ks = 0; ks < 16; ks++)
            Ah[mt][ks] = *(const bf16x8*)(ab + ks * 16);
    }

    u32 key[2][16];
#pragma unroll
    for (int mt = 0; mt < 2; mt++)
#pragma unroll
        for (int g = 0; g < 16; g++) key[mt][g] = 0xffffffffu;

#define STAGE(bufi, kglob_)                                                    \
    {                                                                          \
        int kg_ = (kglob_);                                                    \
        _Pragma("unroll")                                                      \
        for (int c = 0; c < 4; c++) {                                          \
            int chunk = wave * 4 + c;                                          \
            int row = chunk * 2 + (lane >> 5);                                 \
            int g = (lane & 31) ^ (row & 7);                                   \
            const u16* src = cbTh + (size_t)(kg_ + row) * DD + g * 8;          \
            async_load16(src, &tile[bufi][chunk * 512]);                       \
        }                                                                      \
    }

    STAGE(0, ksbase);
    float nc_cur = negC0[ksbase + col];
    __syncthreads();

    for (int kc = 0; kc < 16; kc++) {
        int buf = kc & 1;
        float nc_next = 0.f;
        if (kc < 15) {
            STAGE(buf ^ 1, ksbase + (kc + 1) * KROWS);
            nc_next = negC0[ksbase + (kc + 1) * KROWS + col];
        }

        f32x16 a0, a1;
#pragma unroll
        for (int g = 0; g < 16; g++) { a0[g] = nc_cur; a1[g] = nc_cur; }

        const u16* trow = &tile[buf][col * 256];
#pragma unroll
        for (int ks = 0; ks < 16; ks++) {
            int g = (ks * 2 + half) ^ (col & 7);
            const bf16x8 Bf = *(const bf16x8*)(trow + g * 8);
            a0 = MFMA32_BF16(Ah[0][ks], Bf, a0);
            a1 = MFMA32_BF16(Ah[1][ks], Bf, a1);
        }

        u32 orv = ((u32)kc << 5) | (u32)col;
#pragma unroll
        for (int g = 0; g < 16; g++) {
            u32 kb0 = (f2u(a0[g]) & 0xFFFFFE00u) | orv;
            key[0][g] = min(key[0][g], kb0);
            u32 kb1 = (f2u(a1[g]) & 0xFFFFFE00u) | orv;
            key[1][g] = min(key[1][g], kb1);
        }
        nc_cur = nc_next;
        __syncthreads();  // drains prefetch + guards buffers
    }
#undef STAGE

    // top-2 across the 32 lanes (cols) sharing each C row
#pragma unroll
    for (int mt = 0; mt < 2; mt++) {
#pragma unroll
        for (int g = 0; g < 16; g++) {
            u32 k1 = key[mt][g], k2 = 0xffffffffu;
#pragma unroll
            for (int m = 1; m < 32; m <<= 1) {
                u32 o1 = (u32)__shfl_xor((int)k1, m, 64);
                u32 o2 = (u32)__shfl_xor((int)k2, m, 64);
                u32 mx = max(k1, o1);
                k1 = min(k1, o1);
                k2 = min(min(k2, o2), mx);
            }
            if (col == 0) {
                int row = (g & 3) + 8 * (g >> 2) + 4 * half;
                int n = n0 + mt * 32 + row;
                int base = (n * KSPLIT + blockIdx.y) * 2;
                pkey[base]     = (u32)ksbase + (k1 & 511u);
                pkey[base + 1] = (u32)ksbase + (k2 & 511u);
            }
        }
    }
}

// ---------------------------------------------------------------------------
// K3: exact fp64 rescore of 32 candidates per row. One wave per row.
__global__ __launch_bounds__(256) void k_rescore(const float* __restrict__ xp,
                                                 const float* __restrict__ cbT,
                                                 const u32* __restrict__ pkey,
                                                 u32* __restrict__ idxv,
                                                 float* __restrict__ outIdx,
                                                 float* __restrict__ pmin) {
    int tid = threadIdx.x, wave = tid >> 6, lane = tid & 63;
    int n = blockIdx.x * 4 + wave;
    int sub = lane >> 3;
    int oct = lane & 7;

    f32x4 xv[8];
    const float* xb = xp + n * DD + oct * 32;
#pragma unroll
    for (int t = 0; t < 8; t++) xv[t] = *(const f32x4*)(xb + t * 4);

    u32 myk = pkey[n * 32 + (lane & 31)] & 8191u;

    double bestv = 1e300;
    u32 besti = 0u;
#pragma unroll
    for (int g = 0; g < 4; g++) {
        int c = g * 8 + sub;
        u32 kg = (u32)__shfl((int)myk, c, 64);
        const float* cv = cbT + kg * DD + oct * 32;
        double s = 0.0;
#pragma unroll
        for (int t = 0; t < 8; t++) {
            f32x4 cvv = *(const f32x4*)(cv + t * 4);
#pragma unroll
            for (int q = 0; q < 4; q++) {
                double d = (double)xv[t][q] - (double)cvv[q];
                s += d * d;
            }
        }
        s += __shfl_xor(s, 1, 64);
        s += __shfl_xor(s, 2, 64);
        s += __shfl_xor(s, 4, 64);
        if (s < bestv || (s == bestv && kg < besti)) { bestv = s; besti = kg; }
    }
#pragma unroll
    for (int m = 8; m < 64; m <<= 1) {
        double ov = __shfl_xor(bestv, m, 64);
        u32 oi = (u32)__shfl_xor((int)besti, m, 64);
        if (ov < bestv || (ov == bestv && oi < besti)) { bestv = ov; besti = oi; }
    }
    if (lane == 0) {
        idxv[n] = besti;
        outIdx[n] = (float)besti;
        pmin[n] = (float)bestv;
    }
}

// ---------------------------------------------------------------------------
// K4: diff = sum(pmin)/(N*D), fp64 (pmin in ws, no ordering constraint).
__global__ __launch_bounds__(1024) void k_final(const float* __restrict__ pmin,
                                                float* __restrict__ out) {
    __shared__ double sm[16];
    int tid = threadIdx.x, lane = tid & 63, wv = tid >> 6;
    double s = 0.0;
#pragma unroll
    for (int i = 0; i < 16; i++) s += (double)pmin[i * 1024 + tid];
#pragma unroll
    for (int m = 1; m < 64; m <<= 1) s += __shfl_xor(s, m, 64);
    if (lane == 0) sm[wv] = s;
    __syncthreads();
    if (tid == 0) {
        double t = 0.0;
#pragma unroll
        for (int i = 0; i < 16; i++) t += sm[i];
        out[0] = (float)(t * (1.0 / (double)OUT0));
    }
}

// ---------------------------------------------------------------------------
// K5: gather quantized (B,D,H,W) fp32 via LDS transpose tiles. Rewrites ALL
// of d_out chunk 0 (every scratch byte).
__global__ __launch_bounds__(256) void k_gather(const float* __restrict__ cbT,
                                                const u32* __restrict__ idxv,
                                                float* __restrict__ out0) {
    __shared__ float tile[32 * 260];
    int tid = threadIdx.x;
    int n0 = blockIdx.x * 32;
    int b = n0 >> 10, hw0 = n0 & 1023;

    {
        int r = tid >> 3, seg = tid & 7;
        u32 k = idxv[n0 + r] & 8191u;
        const float* src = cbT + k * DD + seg * 32;
        float* dst = tile + r * 260 + seg * 32;
#pragma unroll
        for (int j = 0; j < 8; j++)
            *(f32x4*)(dst + j * 4) = *(const f32x4*)(src + j * 4);
    }
    __syncthreads();
    {
        int hw = tid & 31, dq = tid >> 5;
        const float* trow = tile + hw * 260;
        float* obase = out0 + ((size_t)b * DD) * HW + hw0 + hw;
#pragma unroll
        for (int dj = 0; dj < 32; dj++) {
            int d = dq * 32 + dj;
            obase[(size_t)d * HW] = trow[d];
        }
    }
}

// ---------------------------------------------------------------------------
extern "C" void kernel_launch(void* const* d_in, const int* in_sizes, int n_in,
                              void* d_out, int out_size, void* d_ws, size_t ws_size,
                              hipStream_t stream) {
    const float* x = nullptr; const float* Wm = nullptr;
    const float* bias = nullptr; const float* cb = nullptr;
    for (int i = 0; i < n_in; i++) {
        switch (in_sizes[i]) {
            case 4194304: x    = (const float*)d_in[i]; break;  // (16,256,32,32)
            case 65536:   Wm   = (const float*)d_in[i]; break;  // (256,256)
            case 256:     bias = (const float*)d_in[i]; break;  // (256,)
            case 2097152: cb   = (const float*)d_in[i]; break;  // (256,8192)
        }
    }

    // d_out is FP32: [quantized (4194304) | diff (1) | indices (16384)]
    float* out0    = (float*)d_out;
    float* outDiff = (float*)d_out + OUT0;
    float* outIdx  = (float*)d_out + OUT0 + 1;

    // Transient scratch inside d_out chunk 0 (16.78 MB; every byte rewritten
    // by k_gather before the harness reads):
    char* o = (char*)d_out;
    u16*   cbTh = (u16*)o;                       // [0, 4 MB)
    u32*   pkey = (u32*)(o + 4194304);           // [4 MB, 6 MB)
    u16*   wh   = (u16*)(o + 6291456);           // 128 KB
    u16*   wm   = (u16*)(o + 6422528);           // 128 KB
    u16*   wl   = (u16*)(o + 6553600);           // 128 KB
    u16*   xpH  = (u16*)(o + 6750208);           // 8 MB  (N,D) bf16 -> ends 14.75 MB

    // Workspace (~25.33 MB, footprint that passed in rounds 4-8):
    char* w = (char*)d_ws;
    float* cbT   = (float*)(w);                  // 8 MB  (K,D) fp32
    float* xp    = (float*)(w + 8388608);        // 16 MB (N,D) fp32
    float* negC0 = (float*)(w + 25165824);       // 32 KB
    u32*   idxv  = (u32*)(w + 25198592);         // 64 KB
    float* pmin  = (float*)(w + 25264128);       // 64 KB

    k_prep<<<2560, 256, 0, stream>>>(cb, Wm, cbT, cbTh, negC0, wh, wm, wl);
    k_proj<<<NN / 64, 256, 0, stream>>>(x, wh, wm, wl, bias, xp, xpH);
    k_dist<<<dim3(NN / 256, KSPLIT), 256, 0, stream>>>(xpH, cbTh, negC0, pkey);
    k_rescore<<<NN / 4, 256, 0, stream>>>(xp, cbT, pkey, idxv, outIdx, pmin);
    k_final<<<1, 1024, 0, stream>>>(pmin, outDiff);
    k_gather<<<NN / 32, 256, 0, stream>>>(cbT, idxv, out0);
}

// Round 10
// 289.489 us; speedup vs baseline: 1.8853x; 1.0072x over previous
//
#include <hip/hip_runtime.h>

typedef short bf16x8 __attribute__((ext_vector_type(8)));
typedef float f32x4 __attribute__((ext_vector_type(4)));
typedef float f32x16 __attribute__((ext_vector_type(16)));
using u16 = unsigned short;
using u32 = unsigned int;

#define MFMA_BF16(A, B, C) __builtin_amdgcn_mfma_f32_16x16x32_bf16((A), (B), (C), 0, 0, 0)
#define MFMA32_BF16(A, B, C) __builtin_amdgcn_mfma_f32_32x32x16_bf16((A), (B), (C), 0, 0, 0)

#define CC 256
#define DD 256
#define KK 8192
#define NN 16384     // B*H*W
#define HW 1024      // H*W
#define OUT0 4194304 // B*D*H*W
#define KSPLIT 16
#define KROWS 32     // k-rows (codes) per LDS tile

static __device__ __forceinline__ float b2f(u16 u) {
    union { u32 i; float f; } v; v.i = ((u32)u) << 16; return v.f;
}
static __device__ __forceinline__ u16 f2b(float f) {  // RNE fp32 -> bf16
    union { float f; u32 i; } v; v.f = f;
    u32 x = v.i;
    u32 r = (x + 0x7fffu + ((x >> 16) & 1u)) >> 16;
    return (u16)r;
}
static __device__ __forceinline__ u32 f2u(float f) {
    union { float f; u32 u; } v; v.f = f; return v.u;
}
static __device__ __forceinline__ void split3(float v, u16& h, u16& m, u16& l) {
    h = f2b(v); float r1 = v - b2f(h);
    m = f2b(r1); float r2 = r1 - b2f(m);
    l = f2b(r2);
}

typedef __attribute__((address_space(1))) const u32 GlbU32;
typedef __attribute__((address_space(3))) u32 LdsU32;
static __device__ __forceinline__ void async_load16(const void* g, void* l) {
    __builtin_amdgcn_global_load_lds((GlbU32*)g, (LdsU32*)l, 16, 0, 0);
}

// ---------------------------------------------------------------------------
// K0 (fused prep): blocks [0,2048): transpose cb -> cbT fp32 + cbTh bf16;
// blocks [2048,2304): negC0[k] = -0.5*(||c_k||^2 + 1024);
// blocks [2304,2560): 3-way bf16 split of conv_w.
__global__ __launch_bounds__(256) void k_prep(const float* __restrict__ cb,
                                              const float* __restrict__ Wm,
                                              float* __restrict__ cbT,
                                              u16* __restrict__ cbTh,
                                              float* __restrict__ negC0,
                                              u16* __restrict__ wh,
                                              u16* __restrict__ wm,
                                              u16* __restrict__ wl) {
    int bx = blockIdx.x, tid = threadIdx.x;
    if (bx < 2048) {
        __shared__ float tile[32][33];
        int k0 = (bx & 255) * 32, d0 = (bx >> 8) * 32;
        int tx = tid & 31, ty = tid >> 5;  // 32 x 8
#pragma unroll
        for (int i = 0; i < 4; i++) {
            int d = d0 + ty + i * 8;
            tile[ty + i * 8][tx] = cb[d * KK + k0 + tx];
        }
        __syncthreads();
#pragma unroll
        for (int i = 0; i < 4; i++) {
            int k = k0 + ty + i * 8;
            float v = tile[tx][ty + i * 8];
            cbT[k * DD + d0 + tx] = v;
            cbTh[k * DD + d0 + tx] = f2b(v);
        }
    } else if (bx < 2304) {
        __shared__ float sm[8][32];
        int kl = tid & 31, dg = tid >> 5;
        int k = (bx - 2048) * 32 + kl;
        float s = 0.f;
#pragma unroll
        for (int j = 0; j < 32; j++) {
            float v = cb[(size_t)(dg * 32 + j) * KK + k];
            s += v * v;
        }
        sm[dg][kl] = s;
        __syncthreads();
        if (tid < 32) {
            float t = 0.f;
#pragma unroll
            for (int g = 0; g < 8; g++) t += sm[g][tid];
            negC0[(bx - 2048) * 32 + tid] = -0.5f * (t + 1024.f);
        }
    } else {
        int t = (bx - 2304) * 256 + tid;
        u16 h, m, l; split3(Wm[t], h, m, l);
        wh[t] = h; wm[t] = m; wl[t] = l;
    }
}

// ---------------------------------------------------------------------------
// K1: xp = x_r @ W^T + b via bf16x3 split MFMA (6 terms ~ fp32 accuracy).
// Parallelism bump: wave = 16 rows x 128 d (dt-half). Block = 4 waves =
// 32 rows x 256 d. Grid NN/32 = 512 -> 2048 waves (2/SIMD, was 1/SIMD).
__global__ __launch_bounds__(256) void k_proj(const float* __restrict__ x,
                                              const u16* __restrict__ wh,
                                              const u16* __restrict__ wm,
                                              const u16* __restrict__ wl,
                                              const float* __restrict__ bias,
                                              float* __restrict__ xp,
                                              u16* __restrict__ xpH) {
    int tid = threadIdx.x;
    int wave = tid >> 6, lane = tid & 63;
    int quad = lane >> 4, l15 = lane & 15;
    int rw = wave >> 1, dh = wave & 1;       // row-group / dt-half
    int n0 = blockIdx.x * 32 + rw * 16;
    int n_a = n0 + l15;
    const float* xb = x + (n_a >> 10) * (CC * HW) + (n_a & (HW - 1));

    f32x4 acc[8];
#pragma unroll
    for (int i = 0; i < 8; i++) acc[i] = (f32x4){0.f, 0.f, 0.f, 0.f};

#pragma unroll
    for (int cc = 0; cc < 8; cc++) {
        bf16x8 ah, am, al;
#pragma unroll
        for (int j = 0; j < 8; j++) {
            float v = xb[(cc * 32 + quad * 8 + j) * HW];
            u16 h, m, l; split3(v, h, m, l);
            ah[j] = (short)h; am[j] = (short)m; al[j] = (short)l;
        }
#pragma unroll
        for (int dt = 0; dt < 8; dt++) {
            int dtg = dh * 8 + dt;
            int off = (dtg * 16 + l15) * CC + cc * 32 + quad * 8;
            const bf16x8 bh = *(const bf16x8*)(wh + off);
            const bf16x8 bm = *(const bf16x8*)(wm + off);
            const bf16x8 bl = *(const bf16x8*)(wl + off);
            acc[dt] = MFMA_BF16(ah, bh, acc[dt]);
            acc[dt] = MFMA_BF16(am, bh, acc[dt]);
            acc[dt] = MFMA_BF16(ah, bm, acc[dt]);
            acc[dt] = MFMA_BF16(al, bh, acc[dt]);
            acc[dt] = MFMA_BF16(am, bm, acc[dt]);
            acc[dt] = MFMA_BF16(ah, bl, acc[dt]);
        }
    }

#pragma unroll
    for (int dt = 0; dt < 8; dt++) {
        int d = (dh * 8 + dt) * 16 + l15;   // C-layout: col = lane&15
        float bv = bias[d];
#pragma unroll
        for (int r = 0; r < 4; r++) {
            int n = n0 + quad * 4 + r;      // C-layout: row = quad*4 + reg
            float v = acc[dt][r] + bv;
            xp[n * DD + d] = v;
            xpH[n * DD + d] = f2b(v);
        }
    }
}

// ---------------------------------------------------------------------------
// K2: approx distance GEMM (32x32x16 MFMA) + fused argmin-candidate select.
// mt=1 (32 rows/wave) to cut registers: Ah 64 VGPR + 2x16 acc (ILP-2 chains,
// chain0 carries the negC0 init) + 16 keys -> ~3 waves/SIMD (was 2).
// Grid (NN/128=128, KSPLIT=16) = 2048 blocks, 8 blocks/CU of work.
// C/D (verified m74/m101): col = lane&31, row = (reg&3)+8*(reg>>2)+4*(lane>>5).
__global__ __launch_bounds__(256, 3) void k_dist(const u16* __restrict__ xpH,
                                                 const u16* __restrict__ cbTh,
                                                 const float* __restrict__ negC0,
                                                 u32* __restrict__ pkey) {
    __shared__ __align__(16) u16 tile[2][KROWS * 256];  // 2 x 16 KB
    int tid = threadIdx.x, wave = tid >> 6, lane = tid & 63;
    int col = lane & 31, half = lane >> 5;
    int n0 = blockIdx.x * 128 + wave * 32;
    int ksbase = blockIdx.y * (KK / KSPLIT);   // 512 codes per split

    // A-frags resident: 16 ks (row = col, dims ks*16 + half*8 + j)
    bf16x8 Ah[16];
    {
        const u16* ab = xpH + (size_t)(n0 + col) * DD + half * 8;
#pragma unroll
        for (int ks = 0; ks < 16; ks++)
            Ah[ks] = *(const bf16x8*)(ab + ks * 16);
    }

    u32 key[16];
#pragma unroll
    for (int g = 0; g < 16; g++) key[g] = 0xffffffffu;

#define STAGE(bufi, kglob_)                                                    \
    {                                                                          \
        int kg_ = (kglob_);                                                    \
        _Pragma("unroll")                                                      \
        for (int c = 0; c < 4; c++) {                                          \
            int chunk = wave * 4 + c;                                          \
            int row = chunk * 2 + (lane >> 5);                                 \
            int g = (lane & 31) ^ (row & 7);                                   \
            const u16* src = cbTh + (size_t)(kg_ + row) * DD + g * 8;          \
            async_load16(src, &tile[bufi][chunk * 512]);                       \
        }                                                                      \
    }

    STAGE(0, ksbase);
    float nc_cur = negC0[ksbase + col];
    __syncthreads();

    for (int kc = 0; kc < 16; kc++) {
        int buf = kc & 1;
        float nc_next = 0.f;
        if (kc < 15) {
            STAGE(buf ^ 1, ksbase + (kc + 1) * KROWS);
            nc_next = negC0[ksbase + (kc + 1) * KROWS + col];
        }

        f32x16 a0, a1;
#pragma unroll
        for (int g = 0; g < 16; g++) { a0[g] = nc_cur; a1[g] = 0.f; }

        const u16* trow = &tile[buf][col * 256];
#pragma unroll
        for (int ks = 0; ks < 8; ks++) {
            int g0 = ((2 * ks) * 2 + half) ^ (col & 7);
            int g1 = ((2 * ks + 1) * 2 + half) ^ (col & 7);
            const bf16x8 Bf0 = *(const bf16x8*)(trow + g0 * 8);
            const bf16x8 Bf1 = *(const bf16x8*)(trow + g1 * 8);
            a0 = MFMA32_BF16(Ah[2 * ks], Bf0, a0);
            a1 = MFMA32_BF16(Ah[2 * ks + 1], Bf1, a1);
        }

        u32 orv = ((u32)kc << 5) | (u32)col;
#pragma unroll
        for (int g = 0; g < 16; g++) {
            u32 kb = (f2u(a0[g] + a1[g]) & 0xFFFFFE00u) | orv;
            key[g] = min(key[g], kb);
        }
        nc_cur = nc_next;
        __syncthreads();  // drains prefetch + guards buffers
    }
#undef STAGE

    // top-2 across the 32 lanes (cols) sharing each C row
#pragma unroll
    for (int g = 0; g < 16; g++) {
        u32 k1 = key[g], k2 = 0xffffffffu;
#pragma unroll
        for (int m = 1; m < 32; m <<= 1) {
            u32 o1 = (u32)__shfl_xor((int)k1, m, 64);
            u32 o2 = (u32)__shfl_xor((int)k2, m, 64);
            u32 mx = max(k1, o1);
            k1 = min(k1, o1);
            k2 = min(min(k2, o2), mx);
        }
        if (col == 0) {
            int row = (g & 3) + 8 * (g >> 2) + 4 * half;
            int n = n0 + row;
            int base = (n * KSPLIT + blockIdx.y) * 2;
            pkey[base]     = (u32)ksbase + (k1 & 511u);
            pkey[base + 1] = (u32)ksbase + (k2 & 511u);
        }
    }
}

// ---------------------------------------------------------------------------
// K3: exact fp64 rescore of 32 candidates per row. One wave per row.
__global__ __launch_bounds__(256) void k_rescore(const float* __restrict__ xp,
                                                 const float* __restrict__ cbT,
                                                 const u32* __restrict__ pkey,
                                                 u32* __restrict__ idxv,
                                                 float* __restrict__ outIdx,
                                                 float* __restrict__ pmin) {
    int tid = threadIdx.x, wave = tid >> 6, lane = tid & 63;
    int n = blockIdx.x * 4 + wave;
    int sub = lane >> 3;
    int oct = lane & 7;

    f32x4 xv[8];
    const float* xb = xp + n * DD + oct * 32;
#pragma unroll
    for (int t = 0; t < 8; t++) xv[t] = *(const f32x4*)(xb + t * 4);

    u32 myk = pkey[n * 32 + (lane & 31)] & 8191u;

    double bestv = 1e300;
    u32 besti = 0u;
#pragma unroll
    for (int g = 0; g < 4; g++) {
        int c = g * 8 + sub;
        u32 kg = (u32)__shfl((int)myk, c, 64);
        const float* cv = cbT + kg * DD + oct * 32;
        double s = 0.0;
#pragma unroll
        for (int t = 0; t < 8; t++) {
            f32x4 cvv = *(const f32x4*)(cv + t * 4);
#pragma unroll
            for (int q = 0; q < 4; q++) {
                double d = (double)xv[t][q] - (double)cvv[q];
                s += d * d;
            }
        }
        s += __shfl_xor(s, 1, 64);
        s += __shfl_xor(s, 2, 64);
        s += __shfl_xor(s, 4, 64);
        if (s < bestv || (s == bestv && kg < besti)) { bestv = s; besti = kg; }
    }
#pragma unroll
    for (int m = 8; m < 64; m <<= 1) {
        double ov = __shfl_xor(bestv, m, 64);
        u32 oi = (u32)__shfl_xor((int)besti, m, 64);
        if (ov < bestv || (ov == bestv && oi < besti)) { bestv = ov; besti = oi; }
    }
    if (lane == 0) {
        idxv[n] = besti;
        outIdx[n] = (float)besti;
        pmin[n] = (float)bestv;
    }
}

// ---------------------------------------------------------------------------
// K4: diff = sum(pmin)/(N*D), fp64 (pmin in ws, no ordering constraint).
__global__ __launch_bounds__(1024) void k_final(const float* __restrict__ pmin,
                                                float* __restrict__ out) {
    __shared__ double sm[16];
    int tid = threadIdx.x, lane = tid & 63, wv = tid >> 6;
    double s = 0.0;
#pragma unroll
    for (int i = 0; i < 16; i++) s += (double)pmin[i * 1024 + tid];
#pragma unroll
    for (int m = 1; m < 64; m <<= 1) s += __shfl_xor(s, m, 64);
    if (lane == 0) sm[wv] = s;
    __syncthreads();
    if (tid == 0) {
        double t = 0.0;
#pragma unroll
        for (int i = 0; i < 16; i++) t += sm[i];
        out[0] = (float)(t * (1.0 / (double)OUT0));
    }
}

// ---------------------------------------------------------------------------
// K5: gather quantized (B,D,H,W) fp32 via LDS transpose tiles. Rewrites ALL
// of d_out chunk 0 (every scratch byte).
__global__ __launch_bounds__(256) void k_gather(const float* __restrict__ cbT,
                                                const u32* __restrict__ idxv,
                                                float* __restrict__ out0) {
    __shared__ float tile[32 * 260];
    int tid = threadIdx.x;
    int n0 = blockIdx.x * 32;
    int b = n0 >> 10, hw0 = n0 & 1023;

    {
        int r = tid >> 3, seg = tid & 7;
        u32 k = idxv[n0 + r] & 8191u;
        const float* src = cbT + k * DD + seg * 32;
        float* dst = tile + r * 260 + seg * 32;
#pragma unroll
        for (int j = 0; j < 8; j++)
            *(f32x4*)(dst + j * 4) = *(const f32x4*)(src + j * 4);
    }
    __syncthreads();
    {
        int hw = tid & 31, dq = tid >> 5;
        const float* trow = tile + hw * 260;
        float* obase = out0 + ((size_t)b * DD) * HW + hw0 + hw;
#pragma unroll
        for (int dj = 0; dj < 32; dj++) {
            int d = dq * 32 + dj;
            obase[(size_t)d * HW] = trow[d];
        }
    }
}

// ---------------------------------------------------------------------------
extern "C" void kernel_launch(void* const* d_in, const int* in_sizes, int n_in,
                              void* d_out, int out_size, void* d_ws, size_t ws_size,
                              hipStream_t stream) {
    const float* x = nullptr; const float* Wm = nullptr;
    const float* bias = nullptr; const float* cb = nullptr;
    for (int i = 0; i < n_in; i++) {
        switch (in_sizes[i]) {
            case 4194304: x    = (const float*)d_in[i]; break;  // (16,256,32,32)
            case 65536:   Wm   = (const float*)d_in[i]; break;  // (256,256)
            case 256:     bias = (const float*)d_in[i]; break;  // (256,)
            case 2097152: cb   = (const float*)d_in[i]; break;  // (256,8192)
        }
    }

    // d_out is FP32: [quantized (4194304) | diff (1) | indices (16384)]
    float* out0    = (float*)d_out;
    float* outDiff = (float*)d_out + OUT0;
    float* outIdx  = (float*)d_out + OUT0 + 1;

    // Transient scratch inside d_out chunk 0 (16.78 MB; every byte rewritten
    // by k_gather before the harness reads):
    char* o = (char*)d_out;
    u16*   cbTh = (u16*)o;                       // [0, 4 MB)
    u32*   pkey = (u32*)(o + 4194304);           // [4 MB, 6 MB)
    u16*   wh   = (u16*)(o + 6291456);           // 128 KB
    u16*   wm   = (u16*)(o + 6422528);           // 128 KB
    u16*   wl   = (u16*)(o + 6553600);           // 128 KB
    u16*   xpH  = (u16*)(o + 6750208);           // 8 MB  (N,D) bf16 -> ends 14.75 MB

    // Workspace (~25.33 MB, footprint that passed in rounds 4-9):
    char* w = (char*)d_ws;
    float* cbT   = (float*)(w);                  // 8 MB  (K,D) fp32
    float* xp    = (float*)(w + 8388608);        // 16 MB (N,D) fp32
    float* negC0 = (float*)(w + 25165824);       // 32 KB
    u32*   idxv  = (u32*)(w + 25198592);         // 64 KB
    float* pmin  = (float*)(w + 25264128);       // 64 KB

    k_prep<<<2560, 256, 0, stream>>>(cb, Wm, cbT, cbTh, negC0, wh, wm, wl);
    k_proj<<<NN / 32, 256, 0, stream>>>(x, wh, wm, wl, bias, xp, xpH);
    k_dist<<<dim3(NN / 128, KSPLIT), 256, 0, stream>>>(xpH, cbTh, negC0, pkey);
    k_rescore<<<NN / 4, 256, 0, stream>>>(xp, cbT, pkey, idxv, outIdx, pmin);
    k_final<<<1, 1024, 0, stream>>>(pmin, outDiff);
    k_gather<<<NN / 32, 256, 0, stream>>>(cbT, idxv, out0);
}